// Round 11
// baseline (1937.808 us; speedup 1.0000x reference)
//
#include <hip/hip_runtime.h>
#include <hip/hip_fp16.h>

#define NHEAD 16
#define DHEAD 128
#define DMODEL 2048
#define SEQ 4096
#define BATCH 4
#define MROWS (BATCH*SEQ)   // 16384

typedef _Float16 f16x8 __attribute__((ext_vector_type(8)));
typedef _Float16 f16x4 __attribute__((ext_vector_type(4)));
typedef float f32x4 __attribute__((ext_vector_type(4)));

// ---------------- fp32 -> fp16 (hi, lo) split, 8 elems/thread ------------
__device__ inline void split8(const float* __restrict__ x, _Float16* __restrict__ hi,
                              _Float16* __restrict__ lo, int i8) {
  float4 v0 = ((const float4*)x)[2 * i8];
  float4 v1 = ((const float4*)x)[2 * i8 + 1];
  f16x8 h, l;
  h[0] = (_Float16)v0.x; h[1] = (_Float16)v0.y;
  h[2] = (_Float16)v0.z; h[3] = (_Float16)v0.w;
  h[4] = (_Float16)v1.x; h[5] = (_Float16)v1.y;
  h[6] = (_Float16)v1.z; h[7] = (_Float16)v1.w;
  ((f16x8*)hi)[i8] = h;
  if (lo) {
    l[0] = (_Float16)(v0.x - (float)h[0]);
    l[1] = (_Float16)(v0.y - (float)h[1]);
    l[2] = (_Float16)(v0.z - (float)h[2]);
    l[3] = (_Float16)(v0.w - (float)h[3]);
    l[4] = (_Float16)(v1.x - (float)h[4]);
    l[5] = (_Float16)(v1.y - (float)h[5]);
    l[6] = (_Float16)(v1.z - (float)h[6]);
    l[7] = (_Float16)(v1.w - (float)h[7]);
    ((f16x8*)lo)[i8] = l;
  }
}

// one matrix per launch (fallback path)
__global__ __launch_bounds__(256) void split_f32_f16(
    const float* __restrict__ x, _Float16* __restrict__ hi,
    _Float16* __restrict__ lo, int n8) {
  int i = blockIdx.x * blockDim.x + threadIdx.x;
  int stride = gridDim.x * blockDim.x;
  for (; i < n8; i += stride) split8(x, hi, lo, i);
}

// all three matrices in one launch (blockIdx.y selects)
__global__ __launch_bounds__(256) void split_all(
    const float* __restrict__ q, const float* __restrict__ k,
    const float* __restrict__ v,
    _Float16* __restrict__ qh, _Float16* __restrict__ ql,
    _Float16* __restrict__ kh, _Float16* __restrict__ kl,
    _Float16* __restrict__ vh, int n8) {
  const float* x; _Float16* hi; _Float16* lo;
  if (blockIdx.y == 0)      { x = q; hi = qh; lo = ql; }
  else if (blockIdx.y == 1) { x = k; hi = kh; lo = kl; }
  else                      { x = v; hi = vh; lo = nullptr; }
  int i = blockIdx.x * blockDim.x + threadIdx.x;
  int stride = gridDim.x * blockDim.x;
  for (; i < n8; i += stride) split8(x, hi, lo, i);
}

// ------------- weight transpose + split: W[K][N] -> WT[N][K] f16 ---------
__device__ inline void transpose_body(const float* __restrict__ W,
                                      _Float16* __restrict__ hi,
                                      _Float16* __restrict__ lo,
                                      int bx, int by, int tx, int ty) {
  __shared__ float tile[32][33];
  int c = bx * 32 + tx;
  for (int r0 = 0; r0 < 32; r0 += 8) {
    int r = by * 32 + ty + r0;
    tile[ty + r0][tx] = W[(size_t)r * DMODEL + c];
  }
  __syncthreads();
  for (int r0 = 0; r0 < 32; r0 += 8) {
    int n = bx * 32 + ty + r0;             // WT row = original col
    int k = by * 32 + tx;                  // WT col = original row
    float v = tile[tx][ty + r0];           // = W[k][n]
    _Float16 h = (_Float16)v;
    hi[(size_t)n * DMODEL + k] = h;
    if (lo) lo[(size_t)n * DMODEL + k] = (_Float16)(v - (float)h);
  }
}

__global__ __launch_bounds__(256) void transpose_split(
    const float* __restrict__ W, _Float16* __restrict__ hi,
    _Float16* __restrict__ lo) {
  transpose_body(W, hi, lo, blockIdx.x, blockIdx.y, threadIdx.x, threadIdx.y);
}

// all four weights in one launch (blockIdx.z selects)
__global__ __launch_bounds__(256) void transpose_all(
    const float* __restrict__ Wq, const float* __restrict__ Wk,
    const float* __restrict__ Wv, const float* __restrict__ Wo,
    _Float16* __restrict__ qh, _Float16* __restrict__ ql,
    _Float16* __restrict__ kh, _Float16* __restrict__ kl,
    _Float16* __restrict__ vh, _Float16* __restrict__ oh) {
  const float* W; _Float16* hi; _Float16* lo;
  switch (blockIdx.z) {
    case 0:  W = Wq; hi = qh; lo = ql;      break;
    case 1:  W = Wk; hi = kh; lo = kl;      break;
    case 2:  W = Wv; hi = vh; lo = nullptr; break;
    default: W = Wo; hi = oh; lo = nullptr; break;
  }
  transpose_body(W, hi, lo, blockIdx.x, blockIdx.y, threadIdx.x, threadIdx.y);
}

// ---- per-head column sums of W, stored TRANSPOSED: CS_T[h][k] -----------
__global__ __launch_bounds__(256) void colsum_f64(
    const float* __restrict__ W, float* __restrict__ CS) {
  const int k = blockIdx.x;                 // row of W
  const int t = threadIdx.x;
  const int h = t >> 4, s = t & 15;
  double acc = 0.0;
  const float* p = W + (size_t)k * DMODEL + h * DHEAD + s * 8;
#pragma unroll
  for (int i = 0; i < 8; i++) acc += (double)p[i];
#pragma unroll
  for (int m = 1; m < 16; m <<= 1) acc += __shfl_xor(acc, m, 64);
  if (s == 0) CS[(size_t)h * DMODEL + k] = (float)acc;
}

// ---- exact per-head row sums, v3: both operands lane-consecutive --------
__global__ __launch_bounds__(256) void rowsum_v3(
    const float* __restrict__ q, const float* __restrict__ k,
    const float* __restrict__ CSq, const float* __restrict__ CSk,
    float* __restrict__ rsQ, float* __restrict__ rsK) {
  const float* X;  const float* CS;  float* rs;
  if (blockIdx.y == 0) { X = q; CS = CSq; rs = rsQ; }
  else                 { X = k; CS = CSk; rs = rsK; }
  const int t = threadIdx.x;
  const int lane = t & 63, w = t >> 6;
  const int row0 = blockIdx.x * 8 + w * 2;     // 2 rows per wave

  const float4* x0 = (const float4*)(X + ((size_t)row0 << 11));
  const float4* x1 = (const float4*)(X + ((size_t)(row0 + 1) << 11));
  float4 xa[8], xb[8];
#pragma unroll
  for (int i = 0; i < 8; i++) {
    xa[i] = x0[i * 64 + lane];
    xb[i] = x1[i * 64 + lane];
  }
  const float4* cs4 = (const float4*)CS;

  for (int h = 0; h < 16; h++) {
    double a0 = 0.0, a1 = 0.0;
#pragma unroll
    for (int i = 0; i < 8; i++) {
      float4 cv = cs4[h * 512 + i * 64 + lane];
      a0 += (double)xa[i].x * (double)cv.x + (double)xa[i].y * (double)cv.y
          + (double)xa[i].z * (double)cv.z + (double)xa[i].w * (double)cv.w;
      a1 += (double)xb[i].x * (double)cv.x + (double)xb[i].y * (double)cv.y
          + (double)xb[i].z * (double)cv.z + (double)xb[i].w * (double)cv.w;
    }
#pragma unroll
    for (int m = 1; m < 64; m <<= 1) {
      a0 += __shfl_xor(a0, m, 64);
      a1 += __shfl_xor(a1, m, 64);
    }
    if (lane == 0) {
      rs[(size_t)row0 * NHEAD + h]       = (float)a0;
      rs[(size_t)(row0 + 1) * NHEAD + h] = (float)a1;
    }
  }
}

// -------------------------- async global->LDS ----------------------------
__device__ inline void glds16(const void* g, void* l) {
  __builtin_amdgcn_global_load_lds(
      (const __attribute__((address_space(1))) unsigned int*)g,
      (__attribute__((address_space(3))) unsigned int*)l, 16, 0, 0);
}

// ========== deep-pipelined 256x256 GEMM, JIT sub-phase schedule ==========
// C[M,N] = A[M,K] @ BT[N,K]^T ; NPASS=3: near-fp32 via hi/lo fp16 split.
// 8 waves (2m x 4n), per-wave 128x64 output. BK=32. Double-buffered LDS.
// Per tile: 8 sub-phases (4 m-pairs x 2 B-halves), ds_reads just-in-time
// with counted lgkm; A registers rotate over {a0,a1,a2} (period-3 tile
// unroll keeps all indexing compile-time); ONE barrier per tile; next
// tile's first read batch issued at the seam so the final sub-phase runs
// under its latency (kills the per-tile cold-read stall that serialized
// LDS and MFMA in R8-R10: MfmaUtil 48%, time = LDS+MFMA sum not max).
// REQUIRES NT % 3 == 1 (true here: NT = 2048/32 = 64).
#define DP_WAIT(n_) do { \
  asm volatile("s_waitcnt lgkmcnt(%0)" :: "n"(n_) : "memory"); \
  __builtin_amdgcn_sched_barrier(0); } while (0)
#define DP_SP(AR, H, P) do { \
  __builtin_amdgcn_s_setprio(1); \
  _Pragma("unroll") \
  for (int i_ = 0; i_ < 2; i_++) \
    _Pragma("unroll") \
    for (int n_ = 0; n_ < 2; n_++) { \
      acc[2*(P)+i_][2*(H)+n_] = __builtin_amdgcn_mfma_f32_16x16x32_f16(AR[i_], bh[H][n_], acc[2*(P)+i_][2*(H)+n_], 0, 0, 0); \
      if constexpr (NPASS == 3) { \
        acc[2*(P)+i_][2*(H)+n_] = __builtin_amdgcn_mfma_f32_16x16x32_f16(AR[i_], bl[H][n_], acc[2*(P)+i_][2*(H)+n_], 0, 0, 0); \
        acc[2*(P)+i_][2*(H)+n_] = __builtin_amdgcn_mfma_f32_16x16x32_f16(AR[2+i_], bh[H][n_], acc[2*(P)+i_][2*(H)+n_], 0, 0, 0); \
      } \
    } \
  __builtin_amdgcn_s_setprio(0); } while (0)

template <int NPASS, int OUT_HALF>
__global__ __launch_bounds__(512, 1) void gemm_dp(
    const _Float16* __restrict__ Ahi, const _Float16* __restrict__ Alo,
    const _Float16* __restrict__ Bhi, const _Float16* __restrict__ Blo,
    float* __restrict__ Cf, _Float16* __restrict__ Ch,
    int M, int N, int Kd) {
  extern __shared__ char smem_raw[];
  constexpr int NMAT = (NPASS == 3) ? 4 : 2;
  constexpr int NLD  = NMAT * 2;                      // glds16 per thread/tile
  constexpr int BUFB = NMAT * 16384;                  // bytes per K-tile buf
  constexpr int BOFF = (NPASS == 3) ? 32768 : 16384;  // Bhi byte offset
  constexpr int U    = (NPASS == 3) ? 4 : 2;          // reads per A-pair/B-half

  const int t = threadIdx.x;
  const int lane = t & 63, wid = t >> 6;
  const int wm = wid >> 2, wn = wid & 3;              // 2 x 4 waves
  const int lr = lane & 15;
  // swizzled per-thread k-byte offset for LDS reads (row-quad = (lr>>1)&3)
  const int lkbs = (((lane >> 4) ^ ((lr >> 1) & 3)) << 4);

  // XCD-chunked bijective swizzle (nwg = 512, %8 == 0)
  const int mtiles = M >> 8, ntiles = N >> 8;
  const int nwg = mtiles * ntiles;
  const int qq = nwg >> 3;
  const int v = (blockIdx.x & 7) * qq + (blockIdx.x >> 3);
  const int m0 = (v / ntiles) << 8, n0 = (v % ntiles) << 8;
  const int NT = Kd >> 5;                             // 64 (NT % 3 == 1)

  f32x4 acc[8][4] = {};
  f16x8 bh[2][2], bl[2][2], a0[4], a1[4], a2[4];

  // staging: 4 base ptrs + 128-row step; source k-chunk pre-swizzled
  const int r0i = t >> 2;
  const int gsx = (t & 3) ^ ((r0i >> 1) & 3);
  const char* gA0 = (const char*)(Ahi + (size_t)(m0 + r0i) * Kd + gsx * 8);
  const char* gB0 = (const char*)(Bhi + (size_t)(n0 + r0i) * Kd + gsx * 8);
  const char* gA1 = nullptr; const char* gB1 = nullptr;
  if constexpr (NPASS == 3) {
    gA1 = (const char*)(Alo + (size_t)(m0 + r0i) * Kd + gsx * 8);
    gB1 = (const char*)(Blo + (size_t)(n0 + r0i) * Kd + gsx * 8);
  }
  const size_t RSTEP = (size_t)128 * Kd * sizeof(_Float16);

  auto STAGE = [&](int kt, int c) {
    char* d = smem_raw + c * BUFB + (t << 4);
    const size_t kb = (size_t)kt << 6;                // kt*32 f16 = 64 B
    glds16(gA0 + kb,         d);
    glds16(gA0 + kb + RSTEP, d + 8192);
    if constexpr (NPASS == 3) {
      glds16(gA1 + kb,         d + 16384);
      glds16(gA1 + kb + RSTEP, d + 24576);
      glds16(gB0 + kb,         d + 32768);
      glds16(gB0 + kb + RSTEP, d + 40960);
      glds16(gB1 + kb,         d + 49152);
      glds16(gB1 + kb + RSTEP, d + 57344);
    } else {
      glds16(gB0 + kb,         d + 16384);
      glds16(gB0 + kb + RSTEP, d + 24576);
    }
  };
  auto RD_BH = [&](const char* buf, int h) {          // U reads
#pragma unroll
    for (int n = 0; n < 2; n++) {
      int row = wn * 64 + (2 * h + n) * 16 + lr;
      bh[h][n] = *(const f16x8*)(buf + BOFF + row * 64 + lkbs);
      if constexpr (NPASS == 3)
        bl[h][n] = *(const f16x8*)(buf + BOFF + 16384 + row * 64 + lkbs);
    }
  };
  auto RD_A = [&](const char* buf, int p, f16x8 (&d)[4]) {  // U reads
#pragma unroll
    for (int i = 0; i < 2; i++) {
      int row = wm * 128 + (2 * p + i) * 16 + lr;
      d[i] = *(const f16x8*)(buf + row * 64 + lkbs);
      if constexpr (NPASS == 3)
        d[2 + i] = *(const f16x8*)(buf + 16384 + row * 64 + lkbs);
    }
  };

  // One tile: rotation (x,y,z) = (p0, p1, p2); p3 re-reads x.
  // Entry: in flight (issue order): Bh0(U), x(U), Bh1(U), y(U).
  auto TILE = [&](f16x8 (&x)[4], f16x8 (&y)[4], f16x8 (&z)[4],
                  int kt, bool pf) {
    const char* buf  = (const char*)smem_raw + (kt & 1) * BUFB;
    const char* bufN = (const char*)smem_raw + ((kt + 1) & 1) * BUFB;
    DP_WAIT(2 * U);            // Bh0, x ready (Bh1, y out)
    DP_SP(x, 0, 0);
    RD_A(buf, 2, z);
    DP_WAIT(2 * U);            // Bh1 ready (y, z out)
    DP_SP(x, 1, 0);
    RD_A(buf, 3, x);
    DP_WAIT(2 * U);            // y ready (z, x' out)
    DP_SP(y, 0, 1);
    DP_SP(y, 1, 1);
    DP_WAIT(U);                // z ready (x' out)
    DP_SP(z, 0, 2);
    DP_SP(z, 1, 2);
    DP_WAIT(0);                // x' ready; ALL reads of buf retired
    DP_SP(x, 0, 3);
    asm volatile("s_waitcnt vmcnt(0)" ::: "memory");   // STAGE(kt+1) landed
    __builtin_amdgcn_sched_barrier(0);
    __builtin_amdgcn_s_barrier();                      // single barrier/tile
    if (kt + 2 < NT) STAGE(kt + 2, kt & 1);
    if (pf) { RD_BH(bufN, 0); RD_A(bufN, 0, y); }      // next p0 -> y
    DP_SP(x, 1, 3);            // runs under seam-read latency
    if (pf) { RD_BH(bufN, 1); RD_A(bufN, 1, z); }      // next p1 -> z
  };

  // prologue
  STAGE(0, 0);
  STAGE(1, 1);
  asm volatile("s_waitcnt vmcnt(%0)" :: "n"(NLD) : "memory");  // tile0 landed
  __builtin_amdgcn_sched_barrier(0);
  __builtin_amdgcn_s_barrier();
  {
    const char* buf0 = (const char*)smem_raw;
    RD_BH(buf0, 0); RD_A(buf0, 0, a0);
    RD_BH(buf0, 1); RD_A(buf0, 1, a1);
  }

  int kt = 0;
  for (int it = 0; it < NT / 3; it++) {                // 21 iters = 63 tiles
    TILE(a0, a1, a2, kt, true); kt++;
    TILE(a1, a2, a0, kt, true); kt++;
    TILE(a2, a0, a1, kt, true); kt++;
  }
  TILE(a0, a1, a2, kt, false);                         // tile NT-1

  // epilogue: C write
#pragma unroll
  for (int mi = 0; mi < 8; mi++) {
    int row = m0 + wm * 128 + mi * 16 + ((lane >> 4) << 2);
#pragma unroll
    for (int n = 0; n < 4; n++) {
      int col = n0 + wn * 64 + n * 16 + (lane & 15);
#pragma unroll
      for (int r = 0; r < 4; r++) {
        if constexpr (OUT_HALF)
          Ch[(size_t)(row + r) * N + col] = (_Float16)acc[mi][n][r];
        else
          Cf[(size_t)(row + r) * N + col] = acc[mi][n][r];
      }
    }
  }
}
#undef DP_WAIT
#undef DP_SP

// ---------------- fallback 128x128 2-phase GEMM (proven) -----------------
template <int NPASS, int OUT_HALF>
__global__ __launch_bounds__(256) void gemm_f16(
    const _Float16* __restrict__ Ahi, const _Float16* __restrict__ Alo,
    const _Float16* __restrict__ Bhi, const _Float16* __restrict__ Blo,
    float* __restrict__ Cf, _Float16* __restrict__ Ch,
    int M, int N, int Kd) {
  constexpr int TILE = 128 * 32;
  __shared__ _Float16 lds[(NPASS == 3 ? 4 : 2) * TILE];
  _Float16* sAh = lds;
  _Float16* sBh = lds + (NPASS == 3 ? 2 : 1) * TILE;
  _Float16* sAl = lds + TILE;
  _Float16* sBl = lds + 3 * TILE;

  const int t = threadIdx.x;
  const int lane = t & 63, wid = t >> 6;
  const int wm = wid >> 1, wn = wid & 1;
  const int lr = lane & 15, lk = (lane >> 4) * 8;

  const int mtiles = M >> 7, ntiles = N >> 7;
  const int nwg = mtiles * ntiles;
  const int qq = nwg >> 3;
  const int v = (blockIdx.x & 7) * qq + (blockIdx.x >> 3);
  const int mx = v / ntiles, ny = v % ntiles;
  const int m0 = mx * 128, n0 = ny * 128;

  f32x4 acc[4][4] = {};

  for (int k0 = 0; k0 < Kd; k0 += 32) {
#pragma unroll
    for (int i = 0; i < 2; i++) {
      int slot = t + i * 256;
      int row = slot >> 2, kc = (slot & 3) * 8;
      glds16(Ahi + (size_t)(m0 + row) * Kd + k0 + kc, sAh + slot * 8);
      glds16(Bhi + (size_t)(n0 + row) * Kd + k0 + kc, sBh + slot * 8);
      if (NPASS == 3) {
        glds16(Alo + (size_t)(m0 + row) * Kd + k0 + kc, sAl + slot * 8);
        glds16(Blo + (size_t)(n0 + row) * Kd + k0 + kc, sBl + slot * 8);
      }
    }
    __syncthreads();

    f16x8 ah[4], bh[4], al[4], bl[4];
#pragma unroll
    for (int f = 0; f < 4; f++) {
      ah[f] = *(const f16x8*)&sAh[(wm * 64 + f * 16 + lr) * 32 + lk];
      bh[f] = *(const f16x8*)&sBh[(wn * 64 + f * 16 + lr) * 32 + lk];
      if (NPASS == 3) {
        al[f] = *(const f16x8*)&sAl[(wm * 64 + f * 16 + lr) * 32 + lk];
        bl[f] = *(const f16x8*)&sBl[(wn * 64 + f * 16 + lr) * 32 + lk];
      }
    }
#pragma unroll
    for (int i = 0; i < 4; i++)
#pragma unroll
      for (int j = 0; j < 4; j++) {
        acc[i][j] = __builtin_amdgcn_mfma_f32_16x16x32_f16(ah[i], bh[j], acc[i][j], 0, 0, 0);
        if (NPASS == 3) {
          acc[i][j] = __builtin_amdgcn_mfma_f32_16x16x32_f16(ah[i], bl[j], acc[i][j], 0, 0, 0);
          acc[i][j] = __builtin_amdgcn_mfma_f32_16x16x32_f16(al[i], bh[j], acc[i][j], 0, 0, 0);
        }
      }
    __syncthreads();
  }

#pragma unroll
  for (int i = 0; i < 4; i++) {
    int row = m0 + wm * 64 + i * 16 + (lane >> 4) * 4;
#pragma unroll
    for (int j = 0; j < 4; j++) {
      int col = n0 + wn * 64 + j * 16 + (lane & 15);
#pragma unroll
      for (int r = 0; r < 4; r++) {
        if (OUT_HALF)
          Ch[(size_t)(row + r) * N + col] = (_Float16)acc[i][j][r];
        else
          Cf[(size_t)(row + r) * N + col] = acc[i][j][r];
      }
    }
  }
}

// -------- per-position head attention: 1 block (256 thr) per (b,s) -------
__global__ __launch_bounds__(256) void attn_kernel(
    const float* __restrict__ Q, const float* __restrict__ K,
    const _Float16* __restrict__ V, const float* __restrict__ mask,
    const float* __restrict__ rsQ, const float* __restrict__ rsK,
    float* __restrict__ wout, _Float16* __restrict__ aout) {
  __shared__ float lq[16][132], lkk[16][132], lv[16][132];
  __shared__ float lw[16][17];
  const int pos = blockIdx.x;
  const int t = threadIdx.x;
  const int h = t >> 4, j = t & 15;
  const size_t rowbase = (size_t)pos * DMODEL + h * DHEAD;

  const float iq = 1.f / (rsQ[(size_t)pos * NHEAD + h] + 1e-6f);
  const float ik = 1.f / (rsK[(size_t)pos * NHEAD + h] + 1e-6f);

  {
    const int dlo = 4 * j, dhi = 64 + 4 * j;
    float4 q0 = *(const float4*)&Q[rowbase + dlo];
    float4 q1 = *(const float4*)&Q[rowbase + dhi];
    q0.x *= iq; q0.y *= iq; q0.z *= iq; q0.w *= iq;
    q1.x *= iq; q1.y *= iq; q1.z *= iq; q1.w *= iq;
    *(float4*)&lq[h][dlo] = q0;
    *(float4*)&lq[h][dhi] = q1;
    float4 k0 = *(const float4*)&K[rowbase + dlo];
    float4 k1 = *(const float4*)&K[rowbase + dhi];
    k0.x *= ik; k0.y *= ik; k0.z *= ik; k0.w *= ik;
    k1.x *= ik; k1.y *= ik; k1.z *= ik; k1.w *= ik;
    *(float4*)&lkk[h][dlo] = k0;
    *(float4*)&lkk[h][dhi] = k1;
    f16x4 v0 = *(const f16x4*)&V[rowbase + dlo];
    f16x4 v1 = *(const f16x4*)&V[rowbase + dhi];
    float4 vf0 = {(float)v0[0], (float)v0[1], (float)v0[2], (float)v0[3]};
    float4 vf1 = {(float)v1[0], (float)v1[1], (float)v1[2], (float)v1[3]};
    *(float4*)&lv[h][dlo] = vf0;
    *(float4*)&lv[h][dhi] = vf1;
  }
  __syncthreads();

  const float4* qr = (const float4*)&lq[h][0];
  const float4* kr = (const float4*)&lkk[j][0];
  float dot = 0.f;
#pragma unroll
  for (int d4 = 0; d4 < 32; d4++) {
    float4 a = qr[d4], b = kr[d4];
    dot = fmaf(a.x, b.x, dot); dot = fmaf(a.y, b.y, dot);
    dot = fmaf(a.z, b.z, dot); dot = fmaf(a.w, b.w, dot);
  }
  float mk = mask[(size_t)pos * 256 + t];
  float x = (dot - 1e9f * mk) * 0.08838834764831845f;  // 1/sqrt(128)
  float mx = x;
#pragma unroll
  for (int m = 1; m < 16; m <<= 1) mx = fmaxf(mx, __shfl_xor(mx, m, 64));
  float e = expf(x - mx);
  float den = e;
#pragma unroll
  for (int m = 1; m < 16; m <<= 1) den += __shfl_xor(den, m, 64);
  float w = e / den;
  wout[(size_t)pos * 256 + t] = w;
  lw[h][j] = w;
  __syncthreads();

  float wreg[16];
#pragma unroll
  for (int k2 = 0; k2 < 16; k2++) wreg[k2] = lw[h][k2];
  float4 a0 = {0.f, 0.f, 0.f, 0.f}, a1 = {0.f, 0.f, 0.f, 0.f};
  const int dlo = 4 * j, dhi = 64 + 4 * j;
#pragma unroll
  for (int k2 = 0; k2 < 16; k2++) {
    float4 v0 = *(const float4*)&lv[k2][dlo];
    float4 v1 = *(const float4*)&lv[k2][dhi];
    float wk = wreg[k2];
    a0.x = fmaf(wk, v0.x, a0.x); a0.y = fmaf(wk, v0.y, a0.y);
    a0.z = fmaf(wk, v0.z, a0.z); a0.w = fmaf(wk, v0.w, a0.w);
    a1.x = fmaf(wk, v1.x, a1.x); a1.y = fmaf(wk, v1.y, a1.y);
    a1.z = fmaf(wk, v1.z, a1.z); a1.w = fmaf(wk, v1.w, a1.w);
  }
  f16x4 o0, o1;
  o0[0] = (_Float16)a0.x; o0[1] = (_Float16)a0.y;
  o0[2] = (_Float16)a0.z; o0[3] = (_Float16)a0.w;
  o1[0] = (_Float16)a1.x; o1[1] = (_Float16)a1.y;
  o1[2] = (_Float16)a1.z; o1[3] = (_Float16)a1.w;
  *(f16x4*)&aout[rowbase + dlo] = o0;
  *(f16x4*)&aout[rowbase + dhi] = o1;
}

// -------------------------------------------------------------------------
extern "C" void kernel_launch(void* const* d_in, const int* in_sizes, int n_in,
                              void* d_out, int out_size, void* d_ws, size_t ws_size,
                              hipStream_t stream) {
  const float* query = (const float*)d_in[0];
  const float* key   = (const float*)d_in[1];
  const float* value = (const float*)d_in[2];
  const float* mask  = (const float*)d_in[3];
  const float* Wq = (const float*)d_in[4];
  const float* Wk = (const float*)d_in[5];
  const float* Wv = (const float*)d_in[6];
  const float* Wo = (const float*)d_in[7];

  float* out  = (float*)d_out;                       // [16384, 2048] fp32
  float* wout = out + (size_t)MROWS * DMODEL;        // [16384, 256] fp32

  const size_t SZ_HALF = (size_t)MROWS * DMODEL * 2; // 67.1 MB
  const size_t SZ_F32  = (size_t)MROWS * DMODEL * 4; // 134.2 MB
  const size_t SZ_W    = (size_t)DMODEL * DMODEL * 2;// 8.4 MB
  const size_t SZ_CS   = (size_t)DMODEL * NHEAD * 4; // 128 KB (fp32)
  const size_t SZ_RS   = (size_t)MROWS * NHEAD * 4;  // 1 MB

  const int n8 = MROWS * DMODEL / 8;
  const int dpgrid = (MROWS / 256) * (DMODEL / 256); // 512 blocks, 1D
  const int ggrid = (MROWS / 128) * (DMODEL / 128);  // fallback grid
  dim3 tgrid4(DMODEL / 32, DMODEL / 32, 4);
  dim3 tgrid(DMODEL / 32, DMODEL / 32);
  dim3 tblk(32, 8);
  dim3 rsgrid(MROWS / 8, 2);
  float* Qbuf = out;   // Q fp32 parked in d_out, overwritten by final GEMM

  const size_t NEED_A = 5 * SZ_HALF + SZ_F32 + 6 * SZ_W + 2 * SZ_CS + 2 * SZ_RS;
  const size_t NEED_B = 3 * SZ_HALF + SZ_F32 + 2 * SZ_W + 2 * SZ_CS + 2 * SZ_RS;
  char* ws = (char*)d_ws;

  if (ws_size >= NEED_A) {
    size_t off = 0;
    _Float16* qh = (_Float16*)(ws + off); off += SZ_HALF;
    _Float16* ql = (_Float16*)(ws + off); off += SZ_HALF;
    _Float16* kh = (_Float16*)(ws + off); off += SZ_HALF;
    _Float16* kl = (_Float16*)(ws + off); off += SZ_HALF;
    _Float16* vh = (_Float16*)(ws + off); off += SZ_HALF;
    float*  Kbuf = (float*)   (ws + off); off += SZ_F32;
    _Float16* wqh = (_Float16*)(ws + off); off += SZ_W;
    _Float16* wql = (_Float16*)(ws + off); off += SZ_W;
    _Float16* wkh = (_Float16*)(ws + off); off += SZ_W;
    _Float16* wkl = (_Float16*)(ws + off); off += SZ_W;
    _Float16* wvh = (_Float16*)(ws + off); off += SZ_W;
    _Float16* woh = (_Float16*)(ws + off); off += SZ_W;
    float* CSq = (float*)(ws + off); off += SZ_CS;
    float* CSk = (float*)(ws + off); off += SZ_CS;
    float* rsQ = (float*)(ws + off); off += SZ_RS;
    float* rsK = (float*)(ws + off); off += SZ_RS;
    _Float16* Vbuf   = qh;   // qh dead after Q-GEMM
    _Float16* attn16 = ql;   // ql dead after Q-GEMM

    colsum_f64<<<DMODEL, 256, 0, stream>>>(Wq, CSq);
    colsum_f64<<<DMODEL, 256, 0, stream>>>(Wk, CSk);
    rowsum_v3<<<rsgrid, 256, 0, stream>>>(query, key, CSq, CSk, rsQ, rsK);
    transpose_all<<<tgrid4, tblk, 0, stream>>>(Wq, Wk, Wv, Wo, wqh, wql, wkh, wkl, wvh, woh);
    split_all<<<dim3(4096, 3), 256, 0, stream>>>(query, key, value, qh, ql, kh, kl, vh, n8);
    gemm_dp<3, 0><<<dpgrid, 512, 131072, stream>>>(qh, ql, wqh, wql, Qbuf, nullptr, MROWS, DMODEL, DMODEL);
    gemm_dp<3, 0><<<dpgrid, 512, 131072, stream>>>(kh, kl, wkh, wkl, Kbuf, nullptr, MROWS, DMODEL, DMODEL);
    gemm_dp<1, 1><<<dpgrid, 512, 65536, stream>>>(vh, nullptr, wvh, nullptr, nullptr, Vbuf, MROWS, DMODEL, DMODEL);
    attn_kernel<<<MROWS, 256, 0, stream>>>(Qbuf, Kbuf, Vbuf, mask, rsQ, rsK, wout, attn16);
    gemm_dp<1, 0><<<dpgrid, 512, 65536, stream>>>(attn16, nullptr, woh, nullptr, out, nullptr, MROWS, DMODEL, DMODEL);
    return;
  }

  if (ws_size < NEED_B) return;  // workspace too small — fail visibly

  // Fallback: sequential-reuse layout with proven 2-phase GEMM
  _Float16* a_hi  = (_Float16*)ws;
  _Float16* a_lo  = (_Float16*)(ws + SZ_HALF);
  float*    Kbuf  = (float*)   (ws + 2 * SZ_HALF);
  _Float16* Vbuf  = (_Float16*)(ws + 2 * SZ_HALF + SZ_F32);
  _Float16* wT_hi = (_Float16*)(ws + 3 * SZ_HALF + SZ_F32);
  _Float16* wT_lo = (_Float16*)(ws + 3 * SZ_HALF + SZ_F32 + SZ_W);
  float*    CSq   = (float*)   (ws + 3 * SZ_HALF + SZ_F32 + 2 * SZ_W);
  float*    CSk   = (float*)   (ws + 3 * SZ_HALF + SZ_F32 + 2 * SZ_W + SZ_CS);
  float*    rsQ   = (float*)   (ws + 3 * SZ_HALF + SZ_F32 + 2 * SZ_W + 2 * SZ_CS);
  float*    rsK   = (float*)   (ws + 3 * SZ_HALF + SZ_F32 + 2 * SZ_W + 2 * SZ_CS + SZ_RS);
  _Float16* attn16 = a_hi;

  colsum_f64<<<DMODEL, 256, 0, stream>>>(Wq, CSq);
  colsum_f64<<<DMODEL, 256, 0, stream>>>(Wk, CSk);
  rowsum_v3<<<rsgrid, 256, 0, stream>>>(query, key, CSq, CSk, rsQ, rsK);

  split_f32_f16<<<4096, 256, 0, stream>>>(query, a_hi, a_lo, n8);
  transpose_split<<<tgrid, tblk, 0, stream>>>(Wq, wT_hi, wT_lo);
  gemm_f16<3, 0><<<ggrid, 256, 0, stream>>>(a_hi, a_lo, wT_hi, wT_lo, Qbuf, nullptr, MROWS, DMODEL, DMODEL);
  split_f32_f16<<<4096, 256, 0, stream>>>(key, a_hi, a_lo, n8);
  transpose_split<<<tgrid, tblk, 0, stream>>>(Wk, wT_hi, wT_lo);
  gemm_f16<3, 0><<<ggrid, 256, 0, stream>>>(a_hi, a_lo, wT_hi, wT_lo, Kbuf, nullptr, MROWS, DMODEL, DMODEL);
  split_f32_f16<<<4096, 256, 0, stream>>>(value, a_hi, nullptr, n8);
  transpose_split<<<tgrid, tblk, 0, stream>>>(Wv, wT_hi, nullptr);
  gemm_f16<1, 1><<<ggrid, 256, 0, stream>>>(a_hi, nullptr, wT_hi, nullptr, nullptr, Vbuf, MROWS, DMODEL, DMODEL);
  attn_kernel<<<MROWS, 256, 0, stream>>>(Qbuf, Kbuf, Vbuf, mask, rsQ, rsK, wout, attn16);
  transpose_split<<<tgrid, tblk, 0, stream>>>(Wo, wT_hi, nullptr);
  gemm_f16<1, 0><<<ggrid, 256, 0, stream>>>(attn16, nullptr, wT_hi, nullptr, out, nullptr, MROWS, DMODEL, DMODEL);
}

// Round 12
// 1550.026 us; speedup vs baseline: 1.2502x; 1.2502x over previous
//
#include <hip/hip_runtime.h>
#include <hip/hip_fp16.h>

#define NHEAD 16
#define DHEAD 128
#define DMODEL 2048
#define SEQ 4096
#define BATCH 4
#define MROWS (BATCH*SEQ)   // 16384

typedef _Float16 f16x8 __attribute__((ext_vector_type(8)));
typedef _Float16 f16x4 __attribute__((ext_vector_type(4)));
typedef float f32x4 __attribute__((ext_vector_type(4)));

// ---------------- fp32 -> fp16 (hi, lo) split, 8 elems/thread ------------
__device__ inline void split8(const float* __restrict__ x, _Float16* __restrict__ hi,
                              _Float16* __restrict__ lo, int i8) {
  float4 v0 = ((const float4*)x)[2 * i8];
  float4 v1 = ((const float4*)x)[2 * i8 + 1];
  f16x8 h, l;
  h[0] = (_Float16)v0.x; h[1] = (_Float16)v0.y;
  h[2] = (_Float16)v0.z; h[3] = (_Float16)v0.w;
  h[4] = (_Float16)v1.x; h[5] = (_Float16)v1.y;
  h[6] = (_Float16)v1.z; h[7] = (_Float16)v1.w;
  ((f16x8*)hi)[i8] = h;
  if (lo) {
    l[0] = (_Float16)(v0.x - (float)h[0]);
    l[1] = (_Float16)(v0.y - (float)h[1]);
    l[2] = (_Float16)(v0.z - (float)h[2]);
    l[3] = (_Float16)(v0.w - (float)h[3]);
    l[4] = (_Float16)(v1.x - (float)h[4]);
    l[5] = (_Float16)(v1.y - (float)h[5]);
    l[6] = (_Float16)(v1.z - (float)h[6]);
    l[7] = (_Float16)(v1.w - (float)h[7]);
    ((f16x8*)lo)[i8] = l;
  }
}

// one matrix per launch (fallback path)
__global__ __launch_bounds__(256) void split_f32_f16(
    const float* __restrict__ x, _Float16* __restrict__ hi,
    _Float16* __restrict__ lo, int n8) {
  int i = blockIdx.x * blockDim.x + threadIdx.x;
  int stride = gridDim.x * blockDim.x;
  for (; i < n8; i += stride) split8(x, hi, lo, i);
}

// all three matrices in one launch (blockIdx.y selects)
__global__ __launch_bounds__(256) void split_all(
    const float* __restrict__ q, const float* __restrict__ k,
    const float* __restrict__ v,
    _Float16* __restrict__ qh, _Float16* __restrict__ ql,
    _Float16* __restrict__ kh, _Float16* __restrict__ kl,
    _Float16* __restrict__ vh, int n8) {
  const float* x; _Float16* hi; _Float16* lo;
  if (blockIdx.y == 0)      { x = q; hi = qh; lo = ql; }
  else if (blockIdx.y == 1) { x = k; hi = kh; lo = kl; }
  else                      { x = v; hi = vh; lo = nullptr; }
  int i = blockIdx.x * blockDim.x + threadIdx.x;
  int stride = gridDim.x * blockDim.x;
  for (; i < n8; i += stride) split8(x, hi, lo, i);
}

// ------------- weight transpose + split: W[K][N] -> WT[N][K] f16 ---------
__device__ inline void transpose_body(const float* __restrict__ W,
                                      _Float16* __restrict__ hi,
                                      _Float16* __restrict__ lo,
                                      int bx, int by, int tx, int ty) {
  __shared__ float tile[32][33];
  int c = bx * 32 + tx;
  for (int r0 = 0; r0 < 32; r0 += 8) {
    int r = by * 32 + ty + r0;
    tile[ty + r0][tx] = W[(size_t)r * DMODEL + c];
  }
  __syncthreads();
  for (int r0 = 0; r0 < 32; r0 += 8) {
    int n = bx * 32 + ty + r0;             // WT row = original col
    int k = by * 32 + tx;                  // WT col = original row
    float v = tile[tx][ty + r0];           // = W[k][n]
    _Float16 h = (_Float16)v;
    hi[(size_t)n * DMODEL + k] = h;
    if (lo) lo[(size_t)n * DMODEL + k] = (_Float16)(v - (float)h);
  }
}

__global__ __launch_bounds__(256) void transpose_split(
    const float* __restrict__ W, _Float16* __restrict__ hi,
    _Float16* __restrict__ lo) {
  transpose_body(W, hi, lo, blockIdx.x, blockIdx.y, threadIdx.x, threadIdx.y);
}

// all four weights in one launch (blockIdx.z selects)
__global__ __launch_bounds__(256) void transpose_all(
    const float* __restrict__ Wq, const float* __restrict__ Wk,
    const float* __restrict__ Wv, const float* __restrict__ Wo,
    _Float16* __restrict__ qh, _Float16* __restrict__ ql,
    _Float16* __restrict__ kh, _Float16* __restrict__ kl,
    _Float16* __restrict__ vh, _Float16* __restrict__ oh) {
  const float* W; _Float16* hi; _Float16* lo;
  switch (blockIdx.z) {
    case 0:  W = Wq; hi = qh; lo = ql;      break;
    case 1:  W = Wk; hi = kh; lo = kl;      break;
    case 2:  W = Wv; hi = vh; lo = nullptr; break;
    default: W = Wo; hi = oh; lo = nullptr; break;
  }
  transpose_body(W, hi, lo, blockIdx.x, blockIdx.y, threadIdx.x, threadIdx.y);
}

// ---- per-head column sums of W, stored TRANSPOSED: CS_T[h][k] -----------
__global__ __launch_bounds__(256) void colsum_f64(
    const float* __restrict__ W, float* __restrict__ CS) {
  const int k = blockIdx.x;                 // row of W
  const int t = threadIdx.x;
  const int h = t >> 4, s = t & 15;
  double acc = 0.0;
  const float* p = W + (size_t)k * DMODEL + h * DHEAD + s * 8;
#pragma unroll
  for (int i = 0; i < 8; i++) acc += (double)p[i];
#pragma unroll
  for (int m = 1; m < 16; m <<= 1) acc += __shfl_xor(acc, m, 64);
  if (s == 0) CS[(size_t)h * DMODEL + k] = (float)acc;
}

// ---- exact per-head row sums, v3: both operands lane-consecutive --------
__global__ __launch_bounds__(256) void rowsum_v3(
    const float* __restrict__ q, const float* __restrict__ k,
    const float* __restrict__ CSq, const float* __restrict__ CSk,
    float* __restrict__ rsQ, float* __restrict__ rsK) {
  const float* X;  const float* CS;  float* rs;
  if (blockIdx.y == 0) { X = q; CS = CSq; rs = rsQ; }
  else                 { X = k; CS = CSk; rs = rsK; }
  const int t = threadIdx.x;
  const int lane = t & 63, w = t >> 6;
  const int row0 = blockIdx.x * 8 + w * 2;     // 2 rows per wave

  const float4* x0 = (const float4*)(X + ((size_t)row0 << 11));
  const float4* x1 = (const float4*)(X + ((size_t)(row0 + 1) << 11));
  float4 xa[8], xb[8];
#pragma unroll
  for (int i = 0; i < 8; i++) {
    xa[i] = x0[i * 64 + lane];
    xb[i] = x1[i * 64 + lane];
  }
  const float4* cs4 = (const float4*)CS;

  for (int h = 0; h < 16; h++) {
    double a0 = 0.0, a1 = 0.0;
#pragma unroll
    for (int i = 0; i < 8; i++) {
      float4 cv = cs4[h * 512 + i * 64 + lane];
      a0 += (double)xa[i].x * (double)cv.x + (double)xa[i].y * (double)cv.y
          + (double)xa[i].z * (double)cv.z + (double)xa[i].w * (double)cv.w;
      a1 += (double)xb[i].x * (double)cv.x + (double)xb[i].y * (double)cv.y
          + (double)xb[i].z * (double)cv.z + (double)xb[i].w * (double)cv.w;
    }
#pragma unroll
    for (int m = 1; m < 64; m <<= 1) {
      a0 += __shfl_xor(a0, m, 64);
      a1 += __shfl_xor(a1, m, 64);
    }
    if (lane == 0) {
      rs[(size_t)row0 * NHEAD + h]       = (float)a0;
      rs[(size_t)(row0 + 1) * NHEAD + h] = (float)a1;
    }
  }
}

// -------------------------- async global->LDS ----------------------------
__device__ inline void glds16(const void* g, void* l) {
  __builtin_amdgcn_global_load_lds(
      (const __attribute__((address_space(1))) unsigned int*)g,
      (__attribute__((address_space(3))) unsigned int*)l, 16, 0, 0);
}

// ========== deep-pipelined 256x256 GEMM, counted vmcnt/lgkmcnt ===========
// C[M,N] = A[M,K] @ BT[N,K]^T ; NPASS=3: near-fp32 via hi/lo fp16 split.
// 8 waves (2m x 4n), per-wave 128x64 output. BK=32. Double-buffered LDS.
// This is the R10 configuration (best measured: 390 us/dispatch, total
// 1552 us). R11's 3-buffer rotation schedule SPILLED (WRITE_SIZE 131->662
// MB = scratch traffic; 128-VGPR cap + 128 AGPR acc) and regressed 50% —
// reverted. acc lives in AGPRs; 120 VGPR + 128 AGPR fits 2 waves/SIMD.
#define DP_LGKM_P() do { \
  if constexpr (NPASS == 3) asm volatile("s_waitcnt lgkmcnt(4)" ::: "memory"); \
  else                      asm volatile("s_waitcnt lgkmcnt(2)" ::: "memory"); \
  __builtin_amdgcn_sched_barrier(0); } while (0)
#define DP_LGKM_0() do { \
  asm volatile("s_waitcnt lgkmcnt(0)" ::: "memory"); \
  __builtin_amdgcn_sched_barrier(0); } while (0)
#define DP_VMCNT_P() do { \
  if constexpr (NPASS == 3) asm volatile("s_waitcnt vmcnt(8)" ::: "memory"); \
  else                      asm volatile("s_waitcnt vmcnt(4)" ::: "memory"); \
  __builtin_amdgcn_sched_barrier(0); } while (0)
#define DP_VMCNT_0() do { \
  asm volatile("s_waitcnt vmcnt(0)" ::: "memory"); \
  __builtin_amdgcn_sched_barrier(0); } while (0)
#define DP_BAR() do { \
  asm volatile("" ::: "memory"); \
  __builtin_amdgcn_s_barrier(); \
  asm volatile("" ::: "memory"); } while (0)
#define DP_QUAD(AR, P) do { \
  __builtin_amdgcn_s_setprio(1); \
  _Pragma("unroll") \
  for (int i_ = 0; i_ < 2; i_++) \
    _Pragma("unroll") \
    for (int n_ = 0; n_ < 4; n_++) { \
      acc[2*(P)+i_][n_] = __builtin_amdgcn_mfma_f32_16x16x32_f16(AR[i_], bhF[n_], acc[2*(P)+i_][n_], 0, 0, 0); \
      if constexpr (NPASS == 3) { \
        acc[2*(P)+i_][n_] = __builtin_amdgcn_mfma_f32_16x16x32_f16(AR[i_], blF[n_], acc[2*(P)+i_][n_], 0, 0, 0); \
        acc[2*(P)+i_][n_] = __builtin_amdgcn_mfma_f32_16x16x32_f16(AR[2+i_], bhF[n_], acc[2*(P)+i_][n_], 0, 0, 0); \
      } \
    } \
  __builtin_amdgcn_s_setprio(0); } while (0)

template <int NPASS, int OUT_HALF>
__global__ __launch_bounds__(512, 1) void gemm_dp(
    const _Float16* __restrict__ Ahi, const _Float16* __restrict__ Alo,
    const _Float16* __restrict__ Bhi, const _Float16* __restrict__ Blo,
    float* __restrict__ Cf, _Float16* __restrict__ Ch,
    int M, int N, int Kd) {
  extern __shared__ char smem_raw[];
  constexpr int NMAT = (NPASS == 3) ? 4 : 2;
  constexpr int NLD  = NMAT * 2;                      // glds16 per thread/tile
  constexpr int BUFB = NMAT * 16384;                  // bytes per K-tile buf
  constexpr int BOFF = (NPASS == 3) ? 32768 : 16384;  // Bhi byte offset

  const int t = threadIdx.x;
  const int lane = t & 63, wid = t >> 6;
  const int wm = wid >> 2, wn = wid & 3;              // 2 x 4 waves
  const int lr = lane & 15;
  // swizzled per-thread k-byte offset for LDS reads (row-quad = (lr>>1)&3)
  const int lkbs = (((lane >> 4) ^ ((lr >> 1) & 3)) << 4);

  // XCD-chunked bijective swizzle (nwg = 512, %8 == 0)
  const int mtiles = M >> 8, ntiles = N >> 8;
  const int nwg = mtiles * ntiles;
  const int qq = nwg >> 3;
  const int v = (blockIdx.x & 7) * qq + (blockIdx.x >> 3);
  const int m0 = (v / ntiles) << 8, n0 = (v % ntiles) << 8;
  const int NT = Kd >> 5;

  f32x4 acc[8][4] = {};
  f16x8 bhF[4], blF[4], aA[4], aB[4];

  // hoisted STAGE addressing: per-thread global base ptrs + LDS dest offs
  const char* gsrc[NLD];
  int ldst[NLD];
#pragma unroll
  for (int j = 0; j < NLD; j++) {
    int s = t + j * 512;                 // slot; runs never cross matrices
    int mm = s >> 10;
    int r = (s & 1023) >> 2;
    int g = s & 3;
    int gs = g ^ ((r >> 1) & 3);         // pre-swizzled source k-chunk
    const _Float16* src; int rb;
    if (mm == 0)      { src = Ahi; rb = m0 + r; }
    else if (mm == 1) { src = (NPASS == 3) ? Alo : Bhi;
                        rb = ((NPASS == 3) ? m0 : n0) + r; }
    else if (mm == 2) { src = Bhi; rb = n0 + r; }
    else              { src = Blo; rb = n0 + r; }
    gsrc[j] = (const char*)(src + (size_t)rb * Kd + gs * 8);
    ldst[j] = s * 16;
  }

  auto STAGE = [&](int kt, int c) {
    char* dstb = smem_raw + c * BUFB;
    const size_t kb = (size_t)kt << 6;   // kt*32 f16 = kt*64 bytes
#pragma unroll
    for (int j = 0; j < NLD; j++)
      glds16(gsrc[j] + kb, dstb + ldst[j]);
  };
  auto RD_B = [&](const char* buf) {
#pragma unroll
    for (int n = 0; n < 4; n++) {
      int row = wn * 64 + n * 16 + lr;
      bhF[n] = *(const f16x8*)(buf + BOFF + row * 64 + lkbs);
      if constexpr (NPASS == 3)
        blF[n] = *(const f16x8*)(buf + BOFF + 16384 + row * 64 + lkbs);
    }
  };
  auto RD_A = [&](const char* buf, int p, f16x8* d) {
#pragma unroll
    for (int i = 0; i < 2; i++) {
      int row = wm * 128 + (2 * p + i) * 16 + lr;
      d[i] = *(const f16x8*)(buf + row * 64 + lkbs);
      if constexpr (NPASS == 3)
        d[2 + i] = *(const f16x8*)(buf + 16384 + row * 64 + lkbs);
    }
  };

  // prologue: tiles 0 and 1 staged; wait tile 0 landed (counted)
  STAGE(0, 0);
  STAGE(1, 1);
  DP_VMCNT_P();
  DP_BAR();

  for (int kt = 0; kt < NT; kt++) {
    const char* buf = (const char*)smem_raw + (kt & 1) * BUFB;
    RD_B(buf);
    RD_A(buf, 0, aA);
    RD_A(buf, 1, aB);
    DP_LGKM_P();                 // B + A-pair0 in regs (A-pair1 in flight)
    DP_QUAD(aA, 0);
    RD_A(buf, 2, aA);
    DP_LGKM_P();                 // A-pair1 ready
    DP_QUAD(aB, 1);
    RD_A(buf, 3, aB);
    DP_LGKM_P();                 // A-pair2 ready
    DP_QUAD(aA, 2);
    DP_LGKM_0();                 // all reads of tile kt done (this wave)
    DP_BAR();                    // ... and block-wide -> safe to overwrite
    if (kt + 2 < NT) {
      STAGE(kt + 2, kt & 1);     // into the buffer we just finished reading
      DP_QUAD(aB, 3);
      DP_VMCNT_P();              // tile kt+1 landed; kt+2 stays in flight
    } else {
      DP_QUAD(aB, 3);
      DP_VMCNT_0();              // epilogue drain
    }
    DP_BAR();                    // publish buf (kt+1)&1
  }

  // epilogue: C write
#pragma unroll
  for (int mi = 0; mi < 8; mi++) {
    int row = m0 + wm * 128 + mi * 16 + ((lane >> 4) << 2);
#pragma unroll
    for (int n = 0; n < 4; n++) {
      int col = n0 + wn * 64 + n * 16 + (lane & 15);
#pragma unroll
      for (int r = 0; r < 4; r++) {
        if constexpr (OUT_HALF)
          Ch[(size_t)(row + r) * N + col] = (_Float16)acc[mi][n][r];
        else
          Cf[(size_t)(row + r) * N + col] = acc[mi][n][r];
      }
    }
  }
}
#undef DP_LGKM_P
#undef DP_LGKM_0
#undef DP_VMCNT_P
#undef DP_VMCNT_0
#undef DP_BAR
#undef DP_QUAD

// ---------------- fallback 128x128 2-phase GEMM (proven) -----------------
template <int NPASS, int OUT_HALF>
__global__ __launch_bounds__(256) void gemm_f16(
    const _Float16* __restrict__ Ahi, const _Float16* __restrict__ Alo,
    const _Float16* __restrict__ Bhi, const _Float16* __restrict__ Blo,
    float* __restrict__ Cf, _Float16* __restrict__ Ch,
    int M, int N, int Kd) {
  constexpr int TILE = 128 * 32;
  __shared__ _Float16 lds[(NPASS == 3 ? 4 : 2) * TILE];
  _Float16* sAh = lds;
  _Float16* sBh = lds + (NPASS == 3 ? 2 : 1) * TILE;
  _Float16* sAl = lds + TILE;
  _Float16* sBl = lds + 3 * TILE;

  const int t = threadIdx.x;
  const int lane = t & 63, wid = t >> 6;
  const int wm = wid >> 1, wn = wid & 1;
  const int lr = lane & 15, lk = (lane >> 4) * 8;

  const int mtiles = M >> 7, ntiles = N >> 7;
  const int nwg = mtiles * ntiles;
  const int qq = nwg >> 3;
  const int v = (blockIdx.x & 7) * qq + (blockIdx.x >> 3);
  const int mx = v / ntiles, ny = v % ntiles;
  const int m0 = mx * 128, n0 = ny * 128;

  f32x4 acc[4][4] = {};

  for (int k0 = 0; k0 < Kd; k0 += 32) {
#pragma unroll
    for (int i = 0; i < 2; i++) {
      int slot = t + i * 256;
      int row = slot >> 2, kc = (slot & 3) * 8;
      glds16(Ahi + (size_t)(m0 + row) * Kd + k0 + kc, sAh + slot * 8);
      glds16(Bhi + (size_t)(n0 + row) * Kd + k0 + kc, sBh + slot * 8);
      if (NPASS == 3) {
        glds16(Alo + (size_t)(m0 + row) * Kd + k0 + kc, sAl + slot * 8);
        glds16(Blo + (size_t)(n0 + row) * Kd + k0 + kc, sBl + slot * 8);
      }
    }
    __syncthreads();

    f16x8 ah[4], bh[4], al[4], bl[4];
#pragma unroll
    for (int f = 0; f < 4; f++) {
      ah[f] = *(const f16x8*)&sAh[(wm * 64 + f * 16 + lr) * 32 + lk];
      bh[f] = *(const f16x8*)&sBh[(wn * 64 + f * 16 + lr) * 32 + lk];
      if (NPASS == 3) {
        al[f] = *(const f16x8*)&sAl[(wm * 64 + f * 16 + lr) * 32 + lk];
        bl[f] = *(const f16x8*)&sBl[(wn * 64 + f * 16 + lr) * 32 + lk];
      }
    }
#pragma unroll
    for (int i = 0; i < 4; i++)
#pragma unroll
      for (int j = 0; j < 4; j++) {
        acc[i][j] = __builtin_amdgcn_mfma_f32_16x16x32_f16(ah[i], bh[j], acc[i][j], 0, 0, 0);
        if (NPASS == 3) {
          acc[i][j] = __builtin_amdgcn_mfma_f32_16x16x32_f16(ah[i], bl[j], acc[i][j], 0, 0, 0);
          acc[i][j] = __builtin_amdgcn_mfma_f32_16x16x32_f16(al[i], bh[j], acc[i][j], 0, 0, 0);
        }
      }
    __syncthreads();
  }

#pragma unroll
  for (int i = 0; i < 4; i++) {
    int row = m0 + wm * 64 + i * 16 + (lane >> 4) * 4;
#pragma unroll
    for (int j = 0; j < 4; j++) {
      int col = n0 + wn * 64 + j * 16 + (lane & 15);
#pragma unroll
      for (int r = 0; r < 4; r++) {
        if (OUT_HALF)
          Ch[(size_t)(row + r) * N + col] = (_Float16)acc[i][j][r];
        else
          Cf[(size_t)(row + r) * N + col] = acc[i][j][r];
      }
    }
  }
}

// -------- per-position head attention: 1 block (256 thr) per (b,s) -------
__global__ __launch_bounds__(256) void attn_kernel(
    const float* __restrict__ Q, const float* __restrict__ K,
    const _Float16* __restrict__ V, const float* __restrict__ mask,
    const float* __restrict__ rsQ, const float* __restrict__ rsK,
    float* __restrict__ wout, _Float16* __restrict__ aout) {
  __shared__ float lq[16][132], lkk[16][132], lv[16][132];
  __shared__ float lw[16][17];
  const int pos = blockIdx.x;
  const int t = threadIdx.x;
  const int h = t >> 4, j = t & 15;
  const size_t rowbase = (size_t)pos * DMODEL + h * DHEAD;

  const float iq = 1.f / (rsQ[(size_t)pos * NHEAD + h] + 1e-6f);
  const float ik = 1.f / (rsK[(size_t)pos * NHEAD + h] + 1e-6f);

  {
    const int dlo = 4 * j, dhi = 64 + 4 * j;
    float4 q0 = *(const float4*)&Q[rowbase + dlo];
    float4 q1 = *(const float4*)&Q[rowbase + dhi];
    q0.x *= iq; q0.y *= iq; q0.z *= iq; q0.w *= iq;
    q1.x *= iq; q1.y *= iq; q1.z *= iq; q1.w *= iq;
    *(float4*)&lq[h][dlo] = q0;
    *(float4*)&lq[h][dhi] = q1;
    float4 k0 = *(const float4*)&K[rowbase + dlo];
    float4 k1 = *(const float4*)&K[rowbase + dhi];
    k0.x *= ik; k0.y *= ik; k0.z *= ik; k0.w *= ik;
    k1.x *= ik; k1.y *= ik; k1.z *= ik; k1.w *= ik;
    *(float4*)&lkk[h][dlo] = k0;
    *(float4*)&lkk[h][dhi] = k1;
    f16x4 v0 = *(const f16x4*)&V[rowbase + dlo];
    f16x4 v1 = *(const f16x4*)&V[rowbase + dhi];
    float4 vf0 = {(float)v0[0], (float)v0[1], (float)v0[2], (float)v0[3]};
    float4 vf1 = {(float)v1[0], (float)v1[1], (float)v1[2], (float)v1[3]};
    *(float4*)&lv[h][dlo] = vf0;
    *(float4*)&lv[h][dhi] = vf1;
  }
  __syncthreads();

  const float4* qr = (const float4*)&lq[h][0];
  const float4* kr = (const float4*)&lkk[j][0];
  float dot = 0.f;
#pragma unroll
  for (int d4 = 0; d4 < 32; d4++) {
    float4 a = qr[d4], b = kr[d4];
    dot = fmaf(a.x, b.x, dot); dot = fmaf(a.y, b.y, dot);
    dot = fmaf(a.z, b.z, dot); dot = fmaf(a.w, b.w, dot);
  }
  float mk = mask[(size_t)pos * 256 + t];
  float x = (dot - 1e9f * mk) * 0.08838834764831845f;  // 1/sqrt(128)
  float mx = x;
#pragma unroll
  for (int m = 1; m < 16; m <<= 1) mx = fmaxf(mx, __shfl_xor(mx, m, 64));
  float e = expf(x - mx);
  float den = e;
#pragma unroll
  for (int m = 1; m < 16; m <<= 1) den += __shfl_xor(den, m, 64);
  float w = e / den;
  wout[(size_t)pos * 256 + t] = w;
  lw[h][j] = w;
  __syncthreads();

  float wreg[16];
#pragma unroll
  for (int k2 = 0; k2 < 16; k2++) wreg[k2] = lw[h][k2];
  float4 a0 = {0.f, 0.f, 0.f, 0.f}, a1 = {0.f, 0.f, 0.f, 0.f};
  const int dlo = 4 * j, dhi = 64 + 4 * j;
#pragma unroll
  for (int k2 = 0; k2 < 16; k2++) {
    float4 v0 = *(const float4*)&lv[k2][dlo];
    float4 v1 = *(const float4*)&lv[k2][dhi];
    float wk = wreg[k2];
    a0.x = fmaf(wk, v0.x, a0.x); a0.y = fmaf(wk, v0.y, a0.y);
    a0.z = fmaf(wk, v0.z, a0.z); a0.w = fmaf(wk, v0.w, a0.w);
    a1.x = fmaf(wk, v1.x, a1.x); a1.y = fmaf(wk, v1.y, a1.y);
    a1.z = fmaf(wk, v1.z, a1.z); a1.w = fmaf(wk, v1.w, a1.w);
  }
  f16x4 o0, o1;
  o0[0] = (_Float16)a0.x; o0[1] = (_Float16)a0.y;
  o0[2] = (_Float16)a0.z; o0[3] = (_Float16)a0.w;
  o1[0] = (_Float16)a1.x; o1[1] = (_Float16)a1.y;
  o1[2] = (_Float16)a1.z; o1[3] = (_Float16)a1.w;
  *(f16x4*)&aout[rowbase + dlo] = o0;
  *(f16x4*)&aout[rowbase + dhi] = o1;
}

// -------------------------------------------------------------------------
extern "C" void kernel_launch(void* const* d_in, const int* in_sizes, int n_in,
                              void* d_out, int out_size, void* d_ws, size_t ws_size,
                              hipStream_t stream) {
  const float* query = (const float*)d_in[0];
  const float* key   = (const float*)d_in[1];
  const float* value = (const float*)d_in[2];
  const float* mask  = (const float*)d_in[3];
  const float* Wq = (const float*)d_in[4];
  const float* Wk = (const float*)d_in[5];
  const float* Wv = (const float*)d_in[6];
  const float* Wo = (const float*)d_in[7];

  float* out  = (float*)d_out;                       // [16384, 2048] fp32
  float* wout = out + (size_t)MROWS * DMODEL;        // [16384, 256] fp32

  const size_t SZ_HALF = (size_t)MROWS * DMODEL * 2; // 67.1 MB
  const size_t SZ_F32  = (size_t)MROWS * DMODEL * 4; // 134.2 MB
  const size_t SZ_W    = (size_t)DMODEL * DMODEL * 2;// 8.4 MB
  const size_t SZ_CS   = (size_t)DMODEL * NHEAD * 4; // 128 KB (fp32)
  const size_t SZ_RS   = (size_t)MROWS * NHEAD * 4;  // 1 MB

  const int n8 = MROWS * DMODEL / 8;
  const int dpgrid = (MROWS / 256) * (DMODEL / 256); // 512 blocks, 1D
  const int ggrid = (MROWS / 128) * (DMODEL / 128);  // fallback grid
  dim3 tgrid4(DMODEL / 32, DMODEL / 32, 4);
  dim3 tgrid(DMODEL / 32, DMODEL / 32);
  dim3 tblk(32, 8);
  dim3 rsgrid(MROWS / 8, 2);
  float* Qbuf = out;   // Q fp32 parked in d_out, overwritten by final GEMM

  const size_t NEED_A = 5 * SZ_HALF + SZ_F32 + 6 * SZ_W + 2 * SZ_CS + 2 * SZ_RS;
  const size_t NEED_B = 3 * SZ_HALF + SZ_F32 + 2 * SZ_W + 2 * SZ_CS + 2 * SZ_RS;
  char* ws = (char*)d_ws;

  if (ws_size >= NEED_A) {
    size_t off = 0;
    _Float16* qh = (_Float16*)(ws + off); off += SZ_HALF;
    _Float16* ql = (_Float16*)(ws + off); off += SZ_HALF;
    _Float16* kh = (_Float16*)(ws + off); off += SZ_HALF;
    _Float16* kl = (_Float16*)(ws + off); off += SZ_HALF;
    _Float16* vh = (_Float16*)(ws + off); off += SZ_HALF;
    float*  Kbuf = (float*)   (ws + off); off += SZ_F32;
    _Float16* wqh = (_Float16*)(ws + off); off += SZ_W;
    _Float16* wql = (_Float16*)(ws + off); off += SZ_W;
    _Float16* wkh = (_Float16*)(ws + off); off += SZ_W;
    _Float16* wkl = (_Float16*)(ws + off); off += SZ_W;
    _Float16* wvh = (_Float16*)(ws + off); off += SZ_W;
    _Float16* woh = (_Float16*)(ws + off); off += SZ_W;
    float* CSq = (float*)(ws + off); off += SZ_CS;
    float* CSk = (float*)(ws + off); off += SZ_CS;
    float* rsQ = (float*)(ws + off); off += SZ_RS;
    float* rsK = (float*)(ws + off); off += SZ_RS;
    _Float16* Vbuf   = qh;   // qh dead after Q-GEMM
    _Float16* attn16 = ql;   // ql dead after Q-GEMM

    colsum_f64<<<DMODEL, 256, 0, stream>>>(Wq, CSq);
    colsum_f64<<<DMODEL, 256, 0, stream>>>(Wk, CSk);
    rowsum_v3<<<rsgrid, 256, 0, stream>>>(query, key, CSq, CSk, rsQ, rsK);
    transpose_all<<<tgrid4, tblk, 0, stream>>>(Wq, Wk, Wv, Wo, wqh, wql, wkh, wkl, wvh, woh);
    split_all<<<dim3(4096, 3), 256, 0, stream>>>(query, key, value, qh, ql, kh, kl, vh, n8);
    gemm_dp<3, 0><<<dpgrid, 512, 131072, stream>>>(qh, ql, wqh, wql, Qbuf, nullptr, MROWS, DMODEL, DMODEL);
    gemm_dp<3, 0><<<dpgrid, 512, 131072, stream>>>(kh, kl, wkh, wkl, Kbuf, nullptr, MROWS, DMODEL, DMODEL);
    gemm_dp<1, 1><<<dpgrid, 512, 65536, stream>>>(vh, nullptr, wvh, nullptr, nullptr, Vbuf, MROWS, DMODEL, DMODEL);
    attn_kernel<<<MROWS, 256, 0, stream>>>(Qbuf, Kbuf, Vbuf, mask, rsQ, rsK, wout, attn16);
    gemm_dp<1, 0><<<dpgrid, 512, 65536, stream>>>(attn16, nullptr, woh, nullptr, out, nullptr, MROWS, DMODEL, DMODEL);
    return;
  }

  if (ws_size < NEED_B) return;  // workspace too small — fail visibly

  // Fallback: sequential-reuse layout with proven 2-phase GEMM
  _Float16* a_hi  = (_Float16*)ws;
  _Float16* a_lo  = (_Float16*)(ws + SZ_HALF);
  float*    Kbuf  = (float*)   (ws + 2 * SZ_HALF);
  _Float16* Vbuf  = (_Float16*)(ws + 2 * SZ_HALF + SZ_F32);
  _Float16* wT_hi = (_Float16*)(ws + 3 * SZ_HALF + SZ_F32);
  _Float16* wT_lo = (_Float16*)(ws + 3 * SZ_HALF + SZ_F32 + SZ_W);
  float*    CSq   = (float*)   (ws + 3 * SZ_HALF + SZ_F32 + 2 * SZ_W);
  float*    CSk   = (float*)   (ws + 3 * SZ_HALF + SZ_F32 + 2 * SZ_W + SZ_CS);
  float*    rsQ   = (float*)   (ws + 3 * SZ_HALF + SZ_F32 + 2 * SZ_W + 2 * SZ_CS);
  float*    rsK   = (float*)   (ws + 3 * SZ_HALF + SZ_F32 + 2 * SZ_W + 2 * SZ_CS + SZ_RS);
  _Float16* attn16 = a_hi;

  colsum_f64<<<DMODEL, 256, 0, stream>>>(Wq, CSq);
  colsum_f64<<<DMODEL, 256, 0, stream>>>(Wk, CSk);
  rowsum_v3<<<rsgrid, 256, 0, stream>>>(query, key, CSq, CSk, rsQ, rsK);

  split_f32_f16<<<4096, 256, 0, stream>>>(query, a_hi, a_lo, n8);
  transpose_split<<<tgrid, tblk, 0, stream>>>(Wq, wT_hi, wT_lo);
  gemm_f16<3, 0><<<ggrid, 256, 0, stream>>>(a_hi, a_lo, wT_hi, wT_lo, Qbuf, nullptr, MROWS, DMODEL, DMODEL);
  split_f32_f16<<<4096, 256, 0, stream>>>(key, a_hi, a_lo, n8);
  transpose_split<<<tgrid, tblk, 0, stream>>>(Wk, wT_hi, wT_lo);
  gemm_f16<3, 0><<<ggrid, 256, 0, stream>>>(a_hi, a_lo, wT_hi, wT_lo, Kbuf, nullptr, MROWS, DMODEL, DMODEL);
  split_f32_f16<<<4096, 256, 0, stream>>>(value, a_hi, nullptr, n8);
  transpose_split<<<tgrid, tblk, 0, stream>>>(Wv, wT_hi, nullptr);
  gemm_f16<1, 1><<<ggrid, 256, 0, stream>>>(a_hi, nullptr, wT_hi, nullptr, nullptr, Vbuf, MROWS, DMODEL, DMODEL);
  attn_kernel<<<MROWS, 256, 0, stream>>>(Qbuf, Kbuf, Vbuf, mask, rsQ, rsK, wout, attn16);
  transpose_split<<<tgrid, tblk, 0, stream>>>(Wo, wT_hi, nullptr);
  gemm_f16<1, 0><<<ggrid, 256, 0, stream>>>(attn16, nullptr, wT_hi, nullptr, out, nullptr, MROWS, DMODEL, DMODEL);
}

// Round 13
// 1463.909 us; speedup vs baseline: 1.3237x; 1.0588x over previous
//
#include <hip/hip_runtime.h>
#include <hip/hip_fp16.h>

#define NHEAD 16
#define DHEAD 128
#define DMODEL 2048
#define SEQ 4096
#define BATCH 4
#define MROWS (BATCH*SEQ)   // 16384

typedef _Float16 f16x8 __attribute__((ext_vector_type(8)));
typedef _Float16 f16x4 __attribute__((ext_vector_type(4)));
typedef float f32x4 __attribute__((ext_vector_type(4)));

// ---------------- fp32 -> fp16 (hi, lo) split, 8 elems/thread ------------
__device__ inline void split8(const float* __restrict__ x, _Float16* __restrict__ hi,
                              _Float16* __restrict__ lo, int i8) {
  float4 v0 = ((const float4*)x)[2 * i8];
  float4 v1 = ((const float4*)x)[2 * i8 + 1];
  f16x8 h, l;
  h[0] = (_Float16)v0.x; h[1] = (_Float16)v0.y;
  h[2] = (_Float16)v0.z; h[3] = (_Float16)v0.w;
  h[4] = (_Float16)v1.x; h[5] = (_Float16)v1.y;
  h[6] = (_Float16)v1.z; h[7] = (_Float16)v1.w;
  ((f16x8*)hi)[i8] = h;
  if (lo) {
    l[0] = (_Float16)(v0.x - (float)h[0]);
    l[1] = (_Float16)(v0.y - (float)h[1]);
    l[2] = (_Float16)(v0.z - (float)h[2]);
    l[3] = (_Float16)(v0.w - (float)h[3]);
    l[4] = (_Float16)(v1.x - (float)h[4]);
    l[5] = (_Float16)(v1.y - (float)h[5]);
    l[6] = (_Float16)(v1.z - (float)h[6]);
    l[7] = (_Float16)(v1.w - (float)h[7]);
    ((f16x8*)lo)[i8] = l;
  }
}

// one matrix per launch (fallback path)
__global__ __launch_bounds__(256) void split_f32_f16(
    const float* __restrict__ x, _Float16* __restrict__ hi,
    _Float16* __restrict__ lo, int n8) {
  int i = blockIdx.x * blockDim.x + threadIdx.x;
  int stride = gridDim.x * blockDim.x;
  for (; i < n8; i += stride) split8(x, hi, lo, i);
}

// ------------- weight transpose + split: W[K][N] -> WT[N][K] f16 ---------
__device__ inline void transpose_body(const float* __restrict__ W,
                                      _Float16* __restrict__ hi,
                                      _Float16* __restrict__ lo,
                                      int bx, int by, int tx, int ty) {
  __shared__ float tile[32][33];
  int c = bx * 32 + tx;
  for (int r0 = 0; r0 < 32; r0 += 8) {
    int r = by * 32 + ty + r0;
    tile[ty + r0][tx] = W[(size_t)r * DMODEL + c];
  }
  __syncthreads();
  for (int r0 = 0; r0 < 32; r0 += 8) {
    int n = bx * 32 + ty + r0;             // WT row = original col
    int k = by * 32 + tx;                  // WT col = original row
    float v = tile[tx][ty + r0];           // = W[k][n]
    _Float16 h = (_Float16)v;
    hi[(size_t)n * DMODEL + k] = h;
    if (lo) lo[(size_t)n * DMODEL + k] = (_Float16)(v - (float)h);
  }
}

__global__ __launch_bounds__(256) void transpose_split(
    const float* __restrict__ W, _Float16* __restrict__ hi,
    _Float16* __restrict__ lo) {
  transpose_body(W, hi, lo, blockIdx.x, blockIdx.y, threadIdx.x, threadIdx.y);
}

// all four weights in one launch (blockIdx.z selects)
__global__ __launch_bounds__(256) void transpose_all(
    const float* __restrict__ Wq, const float* __restrict__ Wk,
    const float* __restrict__ Wv, const float* __restrict__ Wo,
    _Float16* __restrict__ qh, _Float16* __restrict__ ql,
    _Float16* __restrict__ kh, _Float16* __restrict__ kl,
    _Float16* __restrict__ vh, _Float16* __restrict__ oh) {
  const float* W; _Float16* hi; _Float16* lo;
  switch (blockIdx.z) {
    case 0:  W = Wq; hi = qh; lo = ql;      break;
    case 1:  W = Wk; hi = kh; lo = kl;      break;
    case 2:  W = Wv; hi = vh; lo = nullptr; break;
    default: W = Wo; hi = oh; lo = nullptr; break;
  }
  transpose_body(W, hi, lo, blockIdx.x, blockIdx.y, threadIdx.x, threadIdx.y);
}

// ---- per-head column sums of W, stored TRANSPOSED: CS_T[h][k] -----------
__global__ __launch_bounds__(256) void colsum_f64(
    const float* __restrict__ W, float* __restrict__ CS) {
  const int k = blockIdx.x;                 // row of W
  const int t = threadIdx.x;
  const int h = t >> 4, s = t & 15;
  double acc = 0.0;
  const float* p = W + (size_t)k * DMODEL + h * DHEAD + s * 8;
#pragma unroll
  for (int i = 0; i < 8; i++) acc += (double)p[i];
#pragma unroll
  for (int m = 1; m < 16; m <<= 1) acc += __shfl_xor(acc, m, 64);
  if (s == 0) CS[(size_t)h * DMODEL + k] = (float)acc;
}

// both weight colsums in one dispatch (blockIdx.y selects)
__global__ __launch_bounds__(256) void colsum2(
    const float* __restrict__ Wq, const float* __restrict__ Wk,
    float* __restrict__ CSq, float* __restrict__ CSk) {
  const float* W = blockIdx.y ? Wk : Wq;
  float* CS = blockIdx.y ? CSk : CSq;
  const int k = blockIdx.x;
  const int t = threadIdx.x;
  const int h = t >> 4, s = t & 15;
  double acc = 0.0;
  const float* p = W + (size_t)k * DMODEL + h * DHEAD + s * 8;
#pragma unroll
  for (int i = 0; i < 8; i++) acc += (double)p[i];
#pragma unroll
  for (int m = 1; m < 16; m <<= 1) acc += __shfl_xor(acc, m, 64);
  if (s == 0) CS[(size_t)h * DMODEL + k] = (float)acc;
}

// ---- fused activation prep: fp16 split + exact fp64 per-head rowsums ----
// blockIdx.y: 0=q (split->qh,ql + dots vs CSq), 1=k, 2=v (split only).
// Wave owns 2 rows in registers (rowsum_v3 layout: lane owns float4 chunk
// i*64+lane); hi/lo written as coalesced f16x4 (8B/lane); CS read once per
// 2 rows (L2-hot); fp64 accumulate + 64-lane shfl reduce (math identical
// to rowsum_v3 up to fp64 add order ~1e-13). Replaces split_all+rowsum_v3:
// removes the 268MB double-read of q,k and one dispatch.
__global__ __launch_bounds__(256) void prep_qkv(
    const float* __restrict__ q, const float* __restrict__ k,
    const float* __restrict__ v,
    const float* __restrict__ CSq, const float* __restrict__ CSk,
    _Float16* __restrict__ qh, _Float16* __restrict__ ql,
    _Float16* __restrict__ kh, _Float16* __restrict__ kl,
    _Float16* __restrict__ vh,
    float* __restrict__ rsQ, float* __restrict__ rsK) {
  const float* X; const float* CS; float* rs;
  _Float16* hi; _Float16* lo;
  if (blockIdx.y == 0)      { X = q; CS = CSq; rs = rsQ; hi = qh; lo = ql; }
  else if (blockIdx.y == 1) { X = k; CS = CSk; rs = rsK; hi = kh; lo = kl; }
  else                      { X = v; CS = nullptr; rs = nullptr; hi = vh; lo = nullptr; }
  const int t = threadIdx.x;
  const int lane = t & 63, w = t >> 6;
  const int row0 = blockIdx.x * 8 + w * 2;     // 2 rows per wave

  const float4* x0 = (const float4*)(X + ((size_t)row0 << 11));
  const float4* x1 = (const float4*)(X + ((size_t)(row0 + 1) << 11));
  float4 xa[8], xb[8];
#pragma unroll
  for (int i = 0; i < 8; i++) {
    xa[i] = x0[i * 64 + lane];
    xb[i] = x1[i * 64 + lane];
  }

  // split + store: f16x4 per float4 chunk, 8B/lane coalesced
  f16x4* hi4 = (f16x4*)hi;
  f16x4* lo4 = (f16x4*)lo;
  const size_t rb0 = (size_t)row0 << 9;        // row0 * 2048/4
  const size_t rb1 = (size_t)(row0 + 1) << 9;
#pragma unroll
  for (int i = 0; i < 8; i++) {
    int c = i * 64 + lane;
    float4 a = xa[i], b = xb[i];
    f16x4 ha, hb;
    ha[0] = (_Float16)a.x; ha[1] = (_Float16)a.y;
    ha[2] = (_Float16)a.z; ha[3] = (_Float16)a.w;
    hb[0] = (_Float16)b.x; hb[1] = (_Float16)b.y;
    hb[2] = (_Float16)b.z; hb[3] = (_Float16)b.w;
    hi4[rb0 + c] = ha;
    hi4[rb1 + c] = hb;
    if (lo) {
      f16x4 la, lb;
      la[0] = (_Float16)(a.x - (float)ha[0]);
      la[1] = (_Float16)(a.y - (float)ha[1]);
      la[2] = (_Float16)(a.z - (float)ha[2]);
      la[3] = (_Float16)(a.w - (float)ha[3]);
      lb[0] = (_Float16)(b.x - (float)hb[0]);
      lb[1] = (_Float16)(b.y - (float)hb[1]);
      lb[2] = (_Float16)(b.z - (float)hb[2]);
      lb[3] = (_Float16)(b.w - (float)hb[3]);
      lo4[rb0 + c] = la;
      lo4[rb1 + c] = lb;
    }
  }

  // exact fp64 per-head rowsums (q,k only)
  if (CS) {
    const float4* cs4 = (const float4*)CS;
    for (int h = 0; h < 16; h++) {
      double a0 = 0.0, a1 = 0.0;
#pragma unroll
      for (int i = 0; i < 8; i++) {
        float4 cv = cs4[h * 512 + i * 64 + lane];
        a0 += (double)xa[i].x * (double)cv.x + (double)xa[i].y * (double)cv.y
            + (double)xa[i].z * (double)cv.z + (double)xa[i].w * (double)cv.w;
        a1 += (double)xb[i].x * (double)cv.x + (double)xb[i].y * (double)cv.y
            + (double)xb[i].z * (double)cv.z + (double)xb[i].w * (double)cv.w;
      }
#pragma unroll
      for (int m = 1; m < 64; m <<= 1) {
        a0 += __shfl_xor(a0, m, 64);
        a1 += __shfl_xor(a1, m, 64);
      }
      if (lane == 0) {
        rs[(size_t)row0 * NHEAD + h]       = (float)a0;
        rs[(size_t)(row0 + 1) * NHEAD + h] = (float)a1;
      }
    }
  }
}

// ---- exact per-head row sums, v3 (fallback path) ------------------------
__global__ __launch_bounds__(256) void rowsum_v3(
    const float* __restrict__ q, const float* __restrict__ k,
    const float* __restrict__ CSq, const float* __restrict__ CSk,
    float* __restrict__ rsQ, float* __restrict__ rsK) {
  const float* X;  const float* CS;  float* rs;
  if (blockIdx.y == 0) { X = q; CS = CSq; rs = rsQ; }
  else                 { X = k; CS = CSk; rs = rsK; }
  const int t = threadIdx.x;
  const int lane = t & 63, w = t >> 6;
  const int row0 = blockIdx.x * 8 + w * 2;     // 2 rows per wave

  const float4* x0 = (const float4*)(X + ((size_t)row0 << 11));
  const float4* x1 = (const float4*)(X + ((size_t)(row0 + 1) << 11));
  float4 xa[8], xb[8];
#pragma unroll
  for (int i = 0; i < 8; i++) {
    xa[i] = x0[i * 64 + lane];
    xb[i] = x1[i * 64 + lane];
  }
  const float4* cs4 = (const float4*)CS;

  for (int h = 0; h < 16; h++) {
    double a0 = 0.0, a1 = 0.0;
#pragma unroll
    for (int i = 0; i < 8; i++) {
      float4 cv = cs4[h * 512 + i * 64 + lane];
      a0 += (double)xa[i].x * (double)cv.x + (double)xa[i].y * (double)cv.y
          + (double)xa[i].z * (double)cv.z + (double)xa[i].w * (double)cv.w;
      a1 += (double)xb[i].x * (double)cv.x + (double)xb[i].y * (double)cv.y
          + (double)xb[i].z * (double)cv.z + (double)xb[i].w * (double)cv.w;
    }
#pragma unroll
    for (int m = 1; m < 64; m <<= 1) {
      a0 += __shfl_xor(a0, m, 64);
      a1 += __shfl_xor(a1, m, 64);
    }
    if (lane == 0) {
      rs[(size_t)row0 * NHEAD + h]       = (float)a0;
      rs[(size_t)(row0 + 1) * NHEAD + h] = (float)a1;
    }
  }
}

// -------------------------- async global->LDS ----------------------------
__device__ inline void glds16(const void* g, void* l) {
  __builtin_amdgcn_global_load_lds(
      (const __attribute__((address_space(1))) unsigned int*)g,
      (__attribute__((address_space(3))) unsigned int*)l, 16, 0, 0);
}

// ========== deep-pipelined 256x256 GEMM, counted vmcnt/lgkmcnt ===========
// R10 banked configuration (best measured: 390 us/dispatch). Do not edit
// the schedule: R11's deeper rotation spilled (WRITE_SIZE 131->662 MB) and
// regressed 50%. acc lives in AGPRs; 120 VGPR + 128 AGPR fits 2 waves/SIMD.
#define DP_LGKM_P() do { \
  if constexpr (NPASS == 3) asm volatile("s_waitcnt lgkmcnt(4)" ::: "memory"); \
  else                      asm volatile("s_waitcnt lgkmcnt(2)" ::: "memory"); \
  __builtin_amdgcn_sched_barrier(0); } while (0)
#define DP_LGKM_0() do { \
  asm volatile("s_waitcnt lgkmcnt(0)" ::: "memory"); \
  __builtin_amdgcn_sched_barrier(0); } while (0)
#define DP_VMCNT_P() do { \
  if constexpr (NPASS == 3) asm volatile("s_waitcnt vmcnt(8)" ::: "memory"); \
  else                      asm volatile("s_waitcnt vmcnt(4)" ::: "memory"); \
  __builtin_amdgcn_sched_barrier(0); } while (0)
#define DP_VMCNT_0() do { \
  asm volatile("s_waitcnt vmcnt(0)" ::: "memory"); \
  __builtin_amdgcn_sched_barrier(0); } while (0)
#define DP_BAR() do { \
  asm volatile("" ::: "memory"); \
  __builtin_amdgcn_s_barrier(); \
  asm volatile("" ::: "memory"); } while (0)
#define DP_QUAD(AR, P) do { \
  __builtin_amdgcn_s_setprio(1); \
  _Pragma("unroll") \
  for (int i_ = 0; i_ < 2; i_++) \
    _Pragma("unroll") \
    for (int n_ = 0; n_ < 4; n_++) { \
      acc[2*(P)+i_][n_] = __builtin_amdgcn_mfma_f32_16x16x32_f16(AR[i_], bhF[n_], acc[2*(P)+i_][n_], 0, 0, 0); \
      if constexpr (NPASS == 3) { \
        acc[2*(P)+i_][n_] = __builtin_amdgcn_mfma_f32_16x16x32_f16(AR[i_], blF[n_], acc[2*(P)+i_][n_], 0, 0, 0); \
        acc[2*(P)+i_][n_] = __builtin_amdgcn_mfma_f32_16x16x32_f16(AR[2+i_], bhF[n_], acc[2*(P)+i_][n_], 0, 0, 0); \
      } \
    } \
  __builtin_amdgcn_s_setprio(0); } while (0)

template <int NPASS, int OUT_HALF>
__global__ __launch_bounds__(512, 1) void gemm_dp(
    const _Float16* __restrict__ Ahi, const _Float16* __restrict__ Alo,
    const _Float16* __restrict__ Bhi, const _Float16* __restrict__ Blo,
    float* __restrict__ Cf, _Float16* __restrict__ Ch,
    int M, int N, int Kd) {
  extern __shared__ char smem_raw[];
  constexpr int NMAT = (NPASS == 3) ? 4 : 2;
  constexpr int NLD  = NMAT * 2;                      // glds16 per thread/tile
  constexpr int BUFB = NMAT * 16384;                  // bytes per K-tile buf
  constexpr int BOFF = (NPASS == 3) ? 32768 : 16384;  // Bhi byte offset

  const int t = threadIdx.x;
  const int lane = t & 63, wid = t >> 6;
  const int wm = wid >> 2, wn = wid & 3;              // 2 x 4 waves
  const int lr = lane & 15;
  // swizzled per-thread k-byte offset for LDS reads (row-quad = (lr>>1)&3)
  const int lkbs = (((lane >> 4) ^ ((lr >> 1) & 3)) << 4);

  // XCD-chunked bijective swizzle (nwg = 512, %8 == 0)
  const int mtiles = M >> 8, ntiles = N >> 8;
  const int nwg = mtiles * ntiles;
  const int qq = nwg >> 3;
  const int v = (blockIdx.x & 7) * qq + (blockIdx.x >> 3);
  const int m0 = (v / ntiles) << 8, n0 = (v % ntiles) << 8;
  const int NT = Kd >> 5;

  f32x4 acc[8][4] = {};
  f16x8 bhF[4], blF[4], aA[4], aB[4];

  // hoisted STAGE addressing: per-thread global base ptrs + LDS dest offs
  const char* gsrc[NLD];
  int ldst[NLD];
#pragma unroll
  for (int j = 0; j < NLD; j++) {
    int s = t + j * 512;                 // slot; runs never cross matrices
    int mm = s >> 10;
    int r = (s & 1023) >> 2;
    int g = s & 3;
    int gs = g ^ ((r >> 1) & 3);         // pre-swizzled source k-chunk
    const _Float16* src; int rb;
    if (mm == 0)      { src = Ahi; rb = m0 + r; }
    else if (mm == 1) { src = (NPASS == 3) ? Alo : Bhi;
                        rb = ((NPASS == 3) ? m0 : n0) + r; }
    else if (mm == 2) { src = Bhi; rb = n0 + r; }
    else              { src = Blo; rb = n0 + r; }
    gsrc[j] = (const char*)(src + (size_t)rb * Kd + gs * 8);
    ldst[j] = s * 16;
  }

  auto STAGE = [&](int kt, int c) {
    char* dstb = smem_raw + c * BUFB;
    const size_t kb = (size_t)kt << 6;   // kt*32 f16 = kt*64 bytes
#pragma unroll
    for (int j = 0; j < NLD; j++)
      glds16(gsrc[j] + kb, dstb + ldst[j]);
  };
  auto RD_B = [&](const char* buf) {
#pragma unroll
    for (int n = 0; n < 4; n++) {
      int row = wn * 64 + n * 16 + lr;
      bhF[n] = *(const f16x8*)(buf + BOFF + row * 64 + lkbs);
      if constexpr (NPASS == 3)
        blF[n] = *(const f16x8*)(buf + BOFF + 16384 + row * 64 + lkbs);
    }
  };
  auto RD_A = [&](const char* buf, int p, f16x8* d) {
#pragma unroll
    for (int i = 0; i < 2; i++) {
      int row = wm * 128 + (2 * p + i) * 16 + lr;
      d[i] = *(const f16x8*)(buf + row * 64 + lkbs);
      if constexpr (NPASS == 3)
        d[2 + i] = *(const f16x8*)(buf + 16384 + row * 64 + lkbs);
    }
  };

  // prologue: tiles 0 and 1 staged; wait tile 0 landed (counted)
  STAGE(0, 0);
  STAGE(1, 1);
  DP_VMCNT_P();
  DP_BAR();

  for (int kt = 0; kt < NT; kt++) {
    const char* buf = (const char*)smem_raw + (kt & 1) * BUFB;
    RD_B(buf);
    RD_A(buf, 0, aA);
    RD_A(buf, 1, aB);
    DP_LGKM_P();                 // B + A-pair0 in regs (A-pair1 in flight)
    DP_QUAD(aA, 0);
    RD_A(buf, 2, aA);
    DP_LGKM_P();                 // A-pair1 ready
    DP_QUAD(aB, 1);
    RD_A(buf, 3, aB);
    DP_LGKM_P();                 // A-pair2 ready
    DP_QUAD(aA, 2);
    DP_LGKM_0();                 // all reads of tile kt done (this wave)
    DP_BAR();                    // ... and block-wide -> safe to overwrite
    if (kt + 2 < NT) {
      STAGE(kt + 2, kt & 1);     // into the buffer we just finished reading
      DP_QUAD(aB, 3);
      DP_VMCNT_P();              // tile kt+1 landed; kt+2 stays in flight
    } else {
      DP_QUAD(aB, 3);
      DP_VMCNT_0();              // epilogue drain
    }
    DP_BAR();                    // publish buf (kt+1)&1
  }

  // epilogue: C write
#pragma unroll
  for (int mi = 0; mi < 8; mi++) {
    int row = m0 + wm * 128 + mi * 16 + ((lane >> 4) << 2);
#pragma unroll
    for (int n = 0; n < 4; n++) {
      int col = n0 + wn * 64 + n * 16 + (lane & 15);
#pragma unroll
      for (int r = 0; r < 4; r++) {
        if constexpr (OUT_HALF)
          Ch[(size_t)(row + r) * N + col] = (_Float16)acc[mi][n][r];
        else
          Cf[(size_t)(row + r) * N + col] = acc[mi][n][r];
      }
    }
  }
}
#undef DP_LGKM_P
#undef DP_LGKM_0
#undef DP_VMCNT_P
#undef DP_VMCNT_0
#undef DP_BAR
#undef DP_QUAD

// ---------------- fallback 128x128 2-phase GEMM (proven) -----------------
template <int NPASS, int OUT_HALF>
__global__ __launch_bounds__(256) void gemm_f16(
    const _Float16* __restrict__ Ahi, const _Float16* __restrict__ Alo,
    const _Float16* __restrict__ Bhi, const _Float16* __restrict__ Blo,
    float* __restrict__ Cf, _Float16* __restrict__ Ch,
    int M, int N, int Kd) {
  constexpr int TILE = 128 * 32;
  __shared__ _Float16 lds[(NPASS == 3 ? 4 : 2) * TILE];
  _Float16* sAh = lds;
  _Float16* sBh = lds + (NPASS == 3 ? 2 : 1) * TILE;
  _Float16* sAl = lds + TILE;
  _Float16* sBl = lds + 3 * TILE;

  const int t = threadIdx.x;
  const int lane = t & 63, wid = t >> 6;
  const int wm = wid >> 1, wn = wid & 1;
  const int lr = lane & 15, lk = (lane >> 4) * 8;

  const int mtiles = M >> 7, ntiles = N >> 7;
  const int nwg = mtiles * ntiles;
  const int qq = nwg >> 3;
  const int v = (blockIdx.x & 7) * qq + (blockIdx.x >> 3);
  const int mx = v / ntiles, ny = v % ntiles;
  const int m0 = mx * 128, n0 = ny * 128;

  f32x4 acc[4][4] = {};

  for (int k0 = 0; k0 < Kd; k0 += 32) {
#pragma unroll
    for (int i = 0; i < 2; i++) {
      int slot = t + i * 256;
      int row = slot >> 2, kc = (slot & 3) * 8;
      glds16(Ahi + (size_t)(m0 + row) * Kd + k0 + kc, sAh + slot * 8);
      glds16(Bhi + (size_t)(n0 + row) * Kd + k0 + kc, sBh + slot * 8);
      if (NPASS == 3) {
        glds16(Alo + (size_t)(m0 + row) * Kd + k0 + kc, sAl + slot * 8);
        glds16(Blo + (size_t)(n0 + row) * Kd + k0 + kc, sBl + slot * 8);
      }
    }
    __syncthreads();

    f16x8 ah[4], bh[4], al[4], bl[4];
#pragma unroll
    for (int f = 0; f < 4; f++) {
      ah[f] = *(const f16x8*)&sAh[(wm * 64 + f * 16 + lr) * 32 + lk];
      bh[f] = *(const f16x8*)&sBh[(wn * 64 + f * 16 + lr) * 32 + lk];
      if (NPASS == 3) {
        al[f] = *(const f16x8*)&sAl[(wm * 64 + f * 16 + lr) * 32 + lk];
        bl[f] = *(const f16x8*)&sBl[(wn * 64 + f * 16 + lr) * 32 + lk];
      }
    }
#pragma unroll
    for (int i = 0; i < 4; i++)
#pragma unroll
      for (int j = 0; j < 4; j++) {
        acc[i][j] = __builtin_amdgcn_mfma_f32_16x16x32_f16(ah[i], bh[j], acc[i][j], 0, 0, 0);
        if (NPASS == 3) {
          acc[i][j] = __builtin_amdgcn_mfma_f32_16x16x32_f16(ah[i], bl[j], acc[i][j], 0, 0, 0);
          acc[i][j] = __builtin_amdgcn_mfma_f32_16x16x32_f16(al[i], bh[j], acc[i][j], 0, 0, 0);
        }
      }
    __syncthreads();
  }

#pragma unroll
  for (int i = 0; i < 4; i++) {
    int row = m0 + wm * 64 + i * 16 + (lane >> 4) * 4;
#pragma unroll
    for (int j = 0; j < 4; j++) {
      int col = n0 + wn * 64 + j * 16 + (lane & 15);
#pragma unroll
      for (int r = 0; r < 4; r++) {
        if (OUT_HALF)
          Ch[(size_t)(row + r) * N + col] = (_Float16)acc[i][j][r];
        else
          Cf[(size_t)(row + r) * N + col] = acc[i][j][r];
      }
    }
  }
}

// -------- per-position head attention: 1 block (256 thr) per (b,s) -------
__global__ __launch_bounds__(256) void attn_kernel(
    const float* __restrict__ Q, const float* __restrict__ K,
    const _Float16* __restrict__ V, const float* __restrict__ mask,
    const float* __restrict__ rsQ, const float* __restrict__ rsK,
    float* __restrict__ wout, _Float16* __restrict__ aout) {
  __shared__ float lq[16][132], lkk[16][132], lv[16][132];
  __shared__ float lw[16][17];
  const int pos = blockIdx.x;
  const int t = threadIdx.x;
  const int h = t >> 4, j = t & 15;
  const size_t rowbase = (size_t)pos * DMODEL + h * DHEAD;

  const float iq = 1.f / (rsQ[(size_t)pos * NHEAD + h] + 1e-6f);
  const float ik = 1.f / (rsK[(size_t)pos * NHEAD + h] + 1e-6f);

  {
    const int dlo = 4 * j, dhi = 64 + 4 * j;
    float4 q0 = *(const float4*)&Q[rowbase + dlo];
    float4 q1 = *(const float4*)&Q[rowbase + dhi];
    q0.x *= iq; q0.y *= iq; q0.z *= iq; q0.w *= iq;
    q1.x *= iq; q1.y *= iq; q1.z *= iq; q1.w *= iq;
    *(float4*)&lq[h][dlo] = q0;
    *(float4*)&lq[h][dhi] = q1;
    float4 k0 = *(const float4*)&K[rowbase + dlo];
    float4 k1 = *(const float4*)&K[rowbase + dhi];
    k0.x *= ik; k0.y *= ik; k0.z *= ik; k0.w *= ik;
    k1.x *= ik; k1.y *= ik; k1.z *= ik; k1.w *= ik;
    *(float4*)&lkk[h][dlo] = k0;
    *(float4*)&lkk[h][dhi] = k1;
    f16x4 v0 = *(const f16x4*)&V[rowbase + dlo];
    f16x4 v1 = *(const f16x4*)&V[rowbase + dhi];
    float4 vf0 = {(float)v0[0], (float)v0[1], (float)v0[2], (float)v0[3]};
    float4 vf1 = {(float)v1[0], (float)v1[1], (float)v1[2], (float)v1[3]};
    *(float4*)&lv[h][dlo] = vf0;
    *(float4*)&lv[h][dhi] = vf1;
  }
  __syncthreads();

  const float4* qr = (const float4*)&lq[h][0];
  const float4* kr = (const float4*)&lkk[j][0];
  float dot = 0.f;
#pragma unroll
  for (int d4 = 0; d4 < 32; d4++) {
    float4 a = qr[d4], b = kr[d4];
    dot = fmaf(a.x, b.x, dot); dot = fmaf(a.y, b.y, dot);
    dot = fmaf(a.z, b.z, dot); dot = fmaf(a.w, b.w, dot);
  }
  float mk = mask[(size_t)pos * 256 + t];
  float x = (dot - 1e9f * mk) * 0.08838834764831845f;  // 1/sqrt(128)
  float mx = x;
#pragma unroll
  for (int m = 1; m < 16; m <<= 1) mx = fmaxf(mx, __shfl_xor(mx, m, 64));
  float e = expf(x - mx);
  float den = e;
#pragma unroll
  for (int m = 1; m < 16; m <<= 1) den += __shfl_xor(den, m, 64);
  float w = e / den;
  wout[(size_t)pos * 256 + t] = w;
  lw[h][j] = w;
  __syncthreads();

  float wreg[16];
#pragma unroll
  for (int k2 = 0; k2 < 16; k2++) wreg[k2] = lw[h][k2];
  float4 a0 = {0.f, 0.f, 0.f, 0.f}, a1 = {0.f, 0.f, 0.f, 0.f};
  const int dlo = 4 * j, dhi = 64 + 4 * j;
#pragma unroll
  for (int k2 = 0; k2 < 16; k2++) {
    float4 v0 = *(const float4*)&lv[k2][dlo];
    float4 v1 = *(const float4*)&lv[k2][dhi];
    float wk = wreg[k2];
    a0.x = fmaf(wk, v0.x, a0.x); a0.y = fmaf(wk, v0.y, a0.y);
    a0.z = fmaf(wk, v0.z, a0.z); a0.w = fmaf(wk, v0.w, a0.w);
    a1.x = fmaf(wk, v1.x, a1.x); a1.y = fmaf(wk, v1.y, a1.y);
    a1.z = fmaf(wk, v1.z, a1.z); a1.w = fmaf(wk, v1.w, a1.w);
  }
  f16x4 o0, o1;
  o0[0] = (_Float16)a0.x; o0[1] = (_Float16)a0.y;
  o0[2] = (_Float16)a0.z; o0[3] = (_Float16)a0.w;
  o1[0] = (_Float16)a1.x; o1[1] = (_Float16)a1.y;
  o1[2] = (_Float16)a1.z; o1[3] = (_Float16)a1.w;
  *(f16x4*)&aout[rowbase + dlo] = o0;
  *(f16x4*)&aout[rowbase + dhi] = o1;
}

// -------------------------------------------------------------------------
extern "C" void kernel_launch(void* const* d_in, const int* in_sizes, int n_in,
                              void* d_out, int out_size, void* d_ws, size_t ws_size,
                              hipStream_t stream) {
  const float* query = (const float*)d_in[0];
  const float* key   = (const float*)d_in[1];
  const float* value = (const float*)d_in[2];
  const float* mask  = (const float*)d_in[3];
  const float* Wq = (const float*)d_in[4];
  const float* Wk = (const float*)d_in[5];
  const float* Wv = (const float*)d_in[6];
  const float* Wo = (const float*)d_in[7];

  float* out  = (float*)d_out;                       // [16384, 2048] fp32
  float* wout = out + (size_t)MROWS * DMODEL;        // [16384, 256] fp32

  const size_t SZ_HALF = (size_t)MROWS * DMODEL * 2; // 67.1 MB
  const size_t SZ_F32  = (size_t)MROWS * DMODEL * 4; // 134.2 MB
  const size_t SZ_W    = (size_t)DMODEL * DMODEL * 2;// 8.4 MB
  const size_t SZ_CS   = (size_t)DMODEL * NHEAD * 4; // 128 KB (fp32)
  const size_t SZ_RS   = (size_t)MROWS * NHEAD * 4;  // 1 MB

  const int n8 = MROWS * DMODEL / 8;
  const int dpgrid = (MROWS / 256) * (DMODEL / 256); // 512 blocks, 1D
  const int ggrid = (MROWS / 128) * (DMODEL / 128);  // fallback grid
  dim3 tgrid4(DMODEL / 32, DMODEL / 32, 4);
  dim3 tgrid(DMODEL / 32, DMODEL / 32);
  dim3 tblk(32, 8);
  dim3 prepgrid(MROWS / 8, 3);
  dim3 rsgrid(MROWS / 8, 2);
  float* Qbuf = out;   // Q fp32 parked in d_out, overwritten by final GEMM

  const size_t NEED_A = 5 * SZ_HALF + SZ_F32 + 6 * SZ_W + 2 * SZ_CS + 2 * SZ_RS;
  const size_t NEED_B = 3 * SZ_HALF + SZ_F32 + 2 * SZ_W + 2 * SZ_CS + 2 * SZ_RS;
  char* ws = (char*)d_ws;

  if (ws_size >= NEED_A) {
    size_t off = 0;
    _Float16* qh = (_Float16*)(ws + off); off += SZ_HALF;
    _Float16* ql = (_Float16*)(ws + off); off += SZ_HALF;
    _Float16* kh = (_Float16*)(ws + off); off += SZ_HALF;
    _Float16* kl = (_Float16*)(ws + off); off += SZ_HALF;
    _Float16* vh = (_Float16*)(ws + off); off += SZ_HALF;
    float*  Kbuf = (float*)   (ws + off); off += SZ_F32;
    _Float16* wqh = (_Float16*)(ws + off); off += SZ_W;
    _Float16* wql = (_Float16*)(ws + off); off += SZ_W;
    _Float16* wkh = (_Float16*)(ws + off); off += SZ_W;
    _Float16* wkl = (_Float16*)(ws + off); off += SZ_W;
    _Float16* wvh = (_Float16*)(ws + off); off += SZ_W;
    _Float16* woh = (_Float16*)(ws + off); off += SZ_W;
    float* CSq = (float*)(ws + off); off += SZ_CS;
    float* CSk = (float*)(ws + off); off += SZ_CS;
    float* rsQ = (float*)(ws + off); off += SZ_RS;
    float* rsK = (float*)(ws + off); off += SZ_RS;
    _Float16* Vbuf   = qh;   // qh dead after Q-GEMM
    _Float16* attn16 = ql;   // ql dead after Q-GEMM

    colsum2<<<dim3(DMODEL, 2), 256, 0, stream>>>(Wq, Wk, CSq, CSk);
    prep_qkv<<<prepgrid, 256, 0, stream>>>(query, key, value, CSq, CSk,
                                           qh, ql, kh, kl, vh, rsQ, rsK);
    transpose_all<<<tgrid4, tblk, 0, stream>>>(Wq, Wk, Wv, Wo, wqh, wql, wkh, wkl, wvh, woh);
    gemm_dp<3, 0><<<dpgrid, 512, 131072, stream>>>(qh, ql, wqh, wql, Qbuf, nullptr, MROWS, DMODEL, DMODEL);
    gemm_dp<3, 0><<<dpgrid, 512, 131072, stream>>>(kh, kl, wkh, wkl, Kbuf, nullptr, MROWS, DMODEL, DMODEL);
    gemm_dp<1, 1><<<dpgrid, 512, 65536, stream>>>(vh, nullptr, wvh, nullptr, nullptr, Vbuf, MROWS, DMODEL, DMODEL);
    attn_kernel<<<MROWS, 256, 0, stream>>>(Qbuf, Kbuf, Vbuf, mask, rsQ, rsK, wout, attn16);
    gemm_dp<1, 0><<<dpgrid, 512, 65536, stream>>>(attn16, nullptr, woh, nullptr, out, nullptr, MROWS, DMODEL, DMODEL);
    return;
  }

  if (ws_size < NEED_B) return;  // workspace too small — fail visibly

  // Fallback: sequential-reuse layout with proven 2-phase GEMM
  _Float16* a_hi  = (_Float16*)ws;
  _Float16* a_lo  = (_Float16*)(ws + SZ_HALF);
  float*    Kbuf  = (float*)   (ws + 2 * SZ_HALF);
  _Float16* Vbuf  = (_Float16*)(ws + 2 * SZ_HALF + SZ_F32);
  _Float16* wT_hi = (_Float16*)(ws + 3 * SZ_HALF + SZ_F32);
  _Float16* wT_lo = (_Float16*)(ws + 3 * SZ_HALF + SZ_F32 + SZ_W);
  float*    CSq   = (float*)   (ws + 3 * SZ_HALF + SZ_F32 + 2 * SZ_W);
  float*    CSk   = (float*)   (ws + 3 * SZ_HALF + SZ_F32 + 2 * SZ_W + SZ_CS);
  float*    rsQ   = (float*)   (ws + 3 * SZ_HALF + SZ_F32 + 2 * SZ_W + 2 * SZ_CS);
  float*    rsK   = (float*)   (ws + 3 * SZ_HALF + SZ_F32 + 2 * SZ_W + 2 * SZ_CS + SZ_RS);
  _Float16* attn16 = a_hi;

  colsum_f64<<<DMODEL, 256, 0, stream>>>(Wq, CSq);
  colsum_f64<<<DMODEL, 256, 0, stream>>>(Wk, CSk);
  rowsum_v3<<<rsgrid, 256, 0, stream>>>(query, key, CSq, CSk, rsQ, rsK);

  split_f32_f16<<<4096, 256, 0, stream>>>(query, a_hi, a_lo, n8);
  transpose_split<<<tgrid, tblk, 0, stream>>>(Wq, wT_hi, wT_lo);
  gemm_f16<3, 0><<<ggrid, 256, 0, stream>>>(a_hi, a_lo, wT_hi, wT_lo, Qbuf, nullptr, MROWS, DMODEL, DMODEL);
  split_f32_f16<<<4096, 256, 0, stream>>>(key, a_hi, a_lo, n8);
  transpose_split<<<tgrid, tblk, 0, stream>>>(Wk, wT_hi, wT_lo);
  gemm_f16<3, 0><<<ggrid, 256, 0, stream>>>(a_hi, a_lo, wT_hi, wT_lo, Kbuf, nullptr, MROWS, DMODEL, DMODEL);
  split_f32_f16<<<4096, 256, 0, stream>>>(value, a_hi, nullptr, n8);
  transpose_split<<<tgrid, tblk, 0, stream>>>(Wv, wT_hi, nullptr);
  gemm_f16<1, 1><<<ggrid, 256, 0, stream>>>(a_hi, nullptr, wT_hi, nullptr, nullptr, Vbuf, MROWS, DMODEL, DMODEL);
  attn_kernel<<<MROWS, 256, 0, stream>>>(Qbuf, Kbuf, Vbuf, mask, rsQ, rsK, wout, attn16);
  transpose_split<<<tgrid, tblk, 0, stream>>>(Wo, wT_hi, nullptr);
  gemm_f16<1, 0><<<ggrid, 256, 0, stream>>>(attn16, nullptr, wT_hi, nullptr, out, nullptr, MROWS, DMODEL, DMODEL);
}

// Round 14
// 1434.386 us; speedup vs baseline: 1.3510x; 1.0206x over previous
//
#include <hip/hip_runtime.h>
#include <hip/hip_fp16.h>

#define NHEAD 16
#define DHEAD 128
#define DMODEL 2048
#define SEQ 4096
#define BATCH 4
#define MROWS (BATCH*SEQ)   // 16384

typedef _Float16 f16x8 __attribute__((ext_vector_type(8)));
typedef _Float16 f16x4 __attribute__((ext_vector_type(4)));
typedef float f32x4 __attribute__((ext_vector_type(4)));

// ---------------- fp32 -> fp16 (hi, lo) split, 8 elems/thread ------------
__device__ inline void split8(const float* __restrict__ x, _Float16* __restrict__ hi,
                              _Float16* __restrict__ lo, int i8) {
  float4 v0 = ((const float4*)x)[2 * i8];
  float4 v1 = ((const float4*)x)[2 * i8 + 1];
  f16x8 h, l;
  h[0] = (_Float16)v0.x; h[1] = (_Float16)v0.y;
  h[2] = (_Float16)v0.z; h[3] = (_Float16)v0.w;
  h[4] = (_Float16)v1.x; h[5] = (_Float16)v1.y;
  h[6] = (_Float16)v1.z; h[7] = (_Float16)v1.w;
  ((f16x8*)hi)[i8] = h;
  if (lo) {
    l[0] = (_Float16)(v0.x - (float)h[0]);
    l[1] = (_Float16)(v0.y - (float)h[1]);
    l[2] = (_Float16)(v0.z - (float)h[2]);
    l[3] = (_Float16)(v0.w - (float)h[3]);
    l[4] = (_Float16)(v1.x - (float)h[4]);
    l[5] = (_Float16)(v1.y - (float)h[5]);
    l[6] = (_Float16)(v1.z - (float)h[6]);
    l[7] = (_Float16)(v1.w - (float)h[7]);
    ((f16x8*)lo)[i8] = l;
  }
}

// one matrix per launch (fallback path)
__global__ __launch_bounds__(256) void split_f32_f16(
    const float* __restrict__ x, _Float16* __restrict__ hi,
    _Float16* __restrict__ lo, int n8) {
  int i = blockIdx.x * blockDim.x + threadIdx.x;
  int stride = gridDim.x * blockDim.x;
  for (; i < n8; i += stride) split8(x, hi, lo, i);
}

// ------------- weight transpose + split: W[K][N] -> WT[N][K] f16 ---------
__device__ inline void transpose_body(const float* __restrict__ W,
                                      _Float16* __restrict__ hi,
                                      _Float16* __restrict__ lo,
                                      int bx, int by, int tx, int ty) {
  __shared__ float tile[32][33];
  int c = bx * 32 + tx;
  for (int r0 = 0; r0 < 32; r0 += 8) {
    int r = by * 32 + ty + r0;
    tile[ty + r0][tx] = W[(size_t)r * DMODEL + c];
  }
  __syncthreads();
  for (int r0 = 0; r0 < 32; r0 += 8) {
    int n = bx * 32 + ty + r0;             // WT row = original col
    int k = by * 32 + tx;                  // WT col = original row
    float v = tile[tx][ty + r0];           // = W[k][n]
    _Float16 h = (_Float16)v;
    hi[(size_t)n * DMODEL + k] = h;
    if (lo) lo[(size_t)n * DMODEL + k] = (_Float16)(v - (float)h);
  }
}

__global__ __launch_bounds__(256) void transpose_split(
    const float* __restrict__ W, _Float16* __restrict__ hi,
    _Float16* __restrict__ lo) {
  transpose_body(W, hi, lo, blockIdx.x, blockIdx.y, threadIdx.x, threadIdx.y);
}

// all four weights in one launch (blockIdx.z selects)
__global__ __launch_bounds__(256) void transpose_all(
    const float* __restrict__ Wq, const float* __restrict__ Wk,
    const float* __restrict__ Wv, const float* __restrict__ Wo,
    _Float16* __restrict__ qh, _Float16* __restrict__ ql,
    _Float16* __restrict__ kh, _Float16* __restrict__ kl,
    _Float16* __restrict__ vh, _Float16* __restrict__ oh) {
  const float* W; _Float16* hi; _Float16* lo;
  switch (blockIdx.z) {
    case 0:  W = Wq; hi = qh; lo = ql;      break;
    case 1:  W = Wk; hi = kh; lo = kl;      break;
    case 2:  W = Wv; hi = vh; lo = nullptr; break;
    default: W = Wo; hi = oh; lo = nullptr; break;
  }
  transpose_body(W, hi, lo, blockIdx.x, blockIdx.y, threadIdx.x, threadIdx.y);
}

// ---- per-head column sums of W, stored TRANSPOSED: CS_T[h][k] -----------
__global__ __launch_bounds__(256) void colsum_f64(
    const float* __restrict__ W, float* __restrict__ CS) {
  const int k = blockIdx.x;                 // row of W
  const int t = threadIdx.x;
  const int h = t >> 4, s = t & 15;
  double acc = 0.0;
  const float* p = W + (size_t)k * DMODEL + h * DHEAD + s * 8;
#pragma unroll
  for (int i = 0; i < 8; i++) acc += (double)p[i];
#pragma unroll
  for (int m = 1; m < 16; m <<= 1) acc += __shfl_xor(acc, m, 64);
  if (s == 0) CS[(size_t)h * DMODEL + k] = (float)acc;
}

// both weight colsums in one dispatch (blockIdx.y selects)
__global__ __launch_bounds__(256) void colsum2(
    const float* __restrict__ Wq, const float* __restrict__ Wk,
    float* __restrict__ CSq, float* __restrict__ CSk) {
  const float* W = blockIdx.y ? Wk : Wq;
  float* CS = blockIdx.y ? CSk : CSq;
  const int k = blockIdx.x;
  const int t = threadIdx.x;
  const int h = t >> 4, s = t & 15;
  double acc = 0.0;
  const float* p = W + (size_t)k * DMODEL + h * DHEAD + s * 8;
#pragma unroll
  for (int i = 0; i < 8; i++) acc += (double)p[i];
#pragma unroll
  for (int m = 1; m < 16; m <<= 1) acc += __shfl_xor(acc, m, 64);
  if (s == 0) CS[(size_t)h * DMODEL + k] = (float)acc;
}

// ---- fused activation prep: fp16 split + exact fp64 per-head rowsums ----
__global__ __launch_bounds__(256) void prep_qkv(
    const float* __restrict__ q, const float* __restrict__ k,
    const float* __restrict__ v,
    const float* __restrict__ CSq, const float* __restrict__ CSk,
    _Float16* __restrict__ qh, _Float16* __restrict__ ql,
    _Float16* __restrict__ kh, _Float16* __restrict__ kl,
    _Float16* __restrict__ vh,
    float* __restrict__ rsQ, float* __restrict__ rsK) {
  const float* X; const float* CS; float* rs;
  _Float16* hi; _Float16* lo;
  if (blockIdx.y == 0)      { X = q; CS = CSq; rs = rsQ; hi = qh; lo = ql; }
  else if (blockIdx.y == 1) { X = k; CS = CSk; rs = rsK; hi = kh; lo = kl; }
  else                      { X = v; CS = nullptr; rs = nullptr; hi = vh; lo = nullptr; }
  const int t = threadIdx.x;
  const int lane = t & 63, w = t >> 6;
  const int row0 = blockIdx.x * 8 + w * 2;     // 2 rows per wave

  const float4* x0 = (const float4*)(X + ((size_t)row0 << 11));
  const float4* x1 = (const float4*)(X + ((size_t)(row0 + 1) << 11));
  float4 xa[8], xb[8];
#pragma unroll
  for (int i = 0; i < 8; i++) {
    xa[i] = x0[i * 64 + lane];
    xb[i] = x1[i * 64 + lane];
  }

  f16x4* hi4 = (f16x4*)hi;
  f16x4* lo4 = (f16x4*)lo;
  const size_t rb0 = (size_t)row0 << 9;        // row0 * 2048/4
  const size_t rb1 = (size_t)(row0 + 1) << 9;
#pragma unroll
  for (int i = 0; i < 8; i++) {
    int c = i * 64 + lane;
    float4 a = xa[i], b = xb[i];
    f16x4 ha, hb;
    ha[0] = (_Float16)a.x; ha[1] = (_Float16)a.y;
    ha[2] = (_Float16)a.z; ha[3] = (_Float16)a.w;
    hb[0] = (_Float16)b.x; hb[1] = (_Float16)b.y;
    hb[2] = (_Float16)b.z; hb[3] = (_Float16)b.w;
    hi4[rb0 + c] = ha;
    hi4[rb1 + c] = hb;
    if (lo) {
      f16x4 la, lb;
      la[0] = (_Float16)(a.x - (float)ha[0]);
      la[1] = (_Float16)(a.y - (float)ha[1]);
      la[2] = (_Float16)(a.z - (float)ha[2]);
      la[3] = (_Float16)(a.w - (float)ha[3]);
      lb[0] = (_Float16)(b.x - (float)hb[0]);
      lb[1] = (_Float16)(b.y - (float)hb[1]);
      lb[2] = (_Float16)(b.z - (float)hb[2]);
      lb[3] = (_Float16)(b.w - (float)hb[3]);
      lo4[rb0 + c] = la;
      lo4[rb1 + c] = lb;
    }
  }

  if (CS) {
    const float4* cs4 = (const float4*)CS;
    for (int h = 0; h < 16; h++) {
      double a0 = 0.0, a1 = 0.0;
#pragma unroll
      for (int i = 0; i < 8; i++) {
        float4 cv = cs4[h * 512 + i * 64 + lane];
        a0 += (double)xa[i].x * (double)cv.x + (double)xa[i].y * (double)cv.y
            + (double)xa[i].z * (double)cv.z + (double)xa[i].w * (double)cv.w;
        a1 += (double)xb[i].x * (double)cv.x + (double)xb[i].y * (double)cv.y
            + (double)xb[i].z * (double)cv.z + (double)xb[i].w * (double)cv.w;
      }
#pragma unroll
      for (int m = 1; m < 64; m <<= 1) {
        a0 += __shfl_xor(a0, m, 64);
        a1 += __shfl_xor(a1, m, 64);
      }
      if (lane == 0) {
        rs[(size_t)row0 * NHEAD + h]       = (float)a0;
        rs[(size_t)(row0 + 1) * NHEAD + h] = (float)a1;
      }
    }
  }
}

// ---- exact per-head row sums, v3 (fallback path) ------------------------
__global__ __launch_bounds__(256) void rowsum_v3(
    const float* __restrict__ q, const float* __restrict__ k,
    const float* __restrict__ CSq, const float* __restrict__ CSk,
    float* __restrict__ rsQ, float* __restrict__ rsK) {
  const float* X;  const float* CS;  float* rs;
  if (blockIdx.y == 0) { X = q; CS = CSq; rs = rsQ; }
  else                 { X = k; CS = CSk; rs = rsK; }
  const int t = threadIdx.x;
  const int lane = t & 63, w = t >> 6;
  const int row0 = blockIdx.x * 8 + w * 2;     // 2 rows per wave

  const float4* x0 = (const float4*)(X + ((size_t)row0 << 11));
  const float4* x1 = (const float4*)(X + ((size_t)(row0 + 1) << 11));
  float4 xa[8], xb[8];
#pragma unroll
  for (int i = 0; i < 8; i++) {
    xa[i] = x0[i * 64 + lane];
    xb[i] = x1[i * 64 + lane];
  }
  const float4* cs4 = (const float4*)CS;

  for (int h = 0; h < 16; h++) {
    double a0 = 0.0, a1 = 0.0;
#pragma unroll
    for (int i = 0; i < 8; i++) {
      float4 cv = cs4[h * 512 + i * 64 + lane];
      a0 += (double)xa[i].x * (double)cv.x + (double)xa[i].y * (double)cv.y
          + (double)xa[i].z * (double)cv.z + (double)xa[i].w * (double)cv.w;
      a1 += (double)xb[i].x * (double)cv.x + (double)xb[i].y * (double)cv.y
          + (double)xb[i].z * (double)cv.z + (double)xb[i].w * (double)cv.w;
    }
#pragma unroll
    for (int m = 1; m < 64; m <<= 1) {
      a0 += __shfl_xor(a0, m, 64);
      a1 += __shfl_xor(a1, m, 64);
    }
    if (lane == 0) {
      rs[(size_t)row0 * NHEAD + h]       = (float)a0;
      rs[(size_t)(row0 + 1) * NHEAD + h] = (float)a1;
    }
  }
}

// -------------------------- async global->LDS ----------------------------
__device__ inline void glds16(const void* g, void* l) {
  __builtin_amdgcn_global_load_lds(
      (const __attribute__((address_space(1))) unsigned int*)g,
      (__attribute__((address_space(3))) unsigned int*)l, 16, 0, 0);
}

// ========== deep-pipelined 256x256 GEMM body (R10 banked schedule) =======
// Do not edit the schedule: R11's deeper rotation spilled and regressed 50%.
// acc lives in AGPRs; 120 VGPR + 128 AGPR fits 2 waves/SIMD.
#define DP_LGKM_P() do { \
  if constexpr (NPASS == 3) asm volatile("s_waitcnt lgkmcnt(4)" ::: "memory"); \
  else                      asm volatile("s_waitcnt lgkmcnt(2)" ::: "memory"); \
  __builtin_amdgcn_sched_barrier(0); } while (0)
#define DP_LGKM_0() do { \
  asm volatile("s_waitcnt lgkmcnt(0)" ::: "memory"); \
  __builtin_amdgcn_sched_barrier(0); } while (0)
#define DP_VMCNT_P() do { \
  if constexpr (NPASS == 3) asm volatile("s_waitcnt vmcnt(8)" ::: "memory"); \
  else                      asm volatile("s_waitcnt vmcnt(4)" ::: "memory"); \
  __builtin_amdgcn_sched_barrier(0); } while (0)
#define DP_VMCNT_0() do { \
  asm volatile("s_waitcnt vmcnt(0)" ::: "memory"); \
  __builtin_amdgcn_sched_barrier(0); } while (0)
#define DP_BAR() do { \
  asm volatile("" ::: "memory"); \
  __builtin_amdgcn_s_barrier(); \
  asm volatile("" ::: "memory"); } while (0)
#define DP_QUAD(AR, P) do { \
  __builtin_amdgcn_s_setprio(1); \
  _Pragma("unroll") \
  for (int i_ = 0; i_ < 2; i_++) \
    _Pragma("unroll") \
    for (int n_ = 0; n_ < 4; n_++) { \
      acc[2*(P)+i_][n_] = __builtin_amdgcn_mfma_f32_16x16x32_f16(AR[i_], bhF[n_], acc[2*(P)+i_][n_], 0, 0, 0); \
      if constexpr (NPASS == 3) { \
        acc[2*(P)+i_][n_] = __builtin_amdgcn_mfma_f32_16x16x32_f16(AR[i_], blF[n_], acc[2*(P)+i_][n_], 0, 0, 0); \
        acc[2*(P)+i_][n_] = __builtin_amdgcn_mfma_f32_16x16x32_f16(AR[2+i_], bhF[n_], acc[2*(P)+i_][n_], 0, 0, 0); \
      } \
    } \
  __builtin_amdgcn_s_setprio(0); } while (0)

template <int NPASS, int OUT_HALF>
__device__ __forceinline__ void gemm_body(
    int bid, char* smem_raw,
    const _Float16* __restrict__ Ahi, const _Float16* __restrict__ Alo,
    const _Float16* __restrict__ Bhi, const _Float16* __restrict__ Blo,
    float* __restrict__ Cf, _Float16* __restrict__ Ch,
    int M, int N, int Kd) {
  constexpr int NMAT = (NPASS == 3) ? 4 : 2;
  constexpr int NLD  = NMAT * 2;                      // glds16 per thread/tile
  constexpr int BUFB = NMAT * 16384;                  // bytes per K-tile buf
  constexpr int BOFF = (NPASS == 3) ? 32768 : 16384;  // Bhi byte offset

  const int t = threadIdx.x;
  const int lane = t & 63, wid = t >> 6;
  const int wm = wid >> 2, wn = wid & 3;              // 2 x 4 waves
  const int lr = lane & 15;
  // swizzled per-thread k-byte offset for LDS reads (row-quad = (lr>>1)&3)
  const int lkbs = (((lane >> 4) ^ ((lr >> 1) & 3)) << 4);

  // XCD-chunked bijective swizzle (nwg = 512, %8 == 0)
  const int mtiles = M >> 8, ntiles = N >> 8;
  const int nwg = mtiles * ntiles;
  const int qq = nwg >> 3;
  const int v = (bid & 7) * qq + (bid >> 3);
  const int m0 = (v / ntiles) << 8, n0 = (v % ntiles) << 8;
  const int NT = Kd >> 5;

  f32x4 acc[8][4] = {};
  f16x8 bhF[4], blF[4], aA[4], aB[4];

  // hoisted STAGE addressing: per-thread global base ptrs + LDS dest offs
  const char* gsrc[NLD];
  int ldst[NLD];
#pragma unroll
  for (int j = 0; j < NLD; j++) {
    int s = t + j * 512;                 // slot; runs never cross matrices
    int mm = s >> 10;
    int r = (s & 1023) >> 2;
    int g = s & 3;
    int gs = g ^ ((r >> 1) & 3);         // pre-swizzled source k-chunk
    const _Float16* src; int rb;
    if (mm == 0)      { src = Ahi; rb = m0 + r; }
    else if (mm == 1) { src = (NPASS == 3) ? Alo : Bhi;
                        rb = ((NPASS == 3) ? m0 : n0) + r; }
    else if (mm == 2) { src = Bhi; rb = n0 + r; }
    else              { src = Blo; rb = n0 + r; }
    gsrc[j] = (const char*)(src + (size_t)rb * Kd + gs * 8);
    ldst[j] = s * 16;
  }

  auto STAGE = [&](int kt, int c) {
    char* dstb = smem_raw + c * BUFB;
    const size_t kb = (size_t)kt << 6;   // kt*32 f16 = kt*64 bytes
#pragma unroll
    for (int j = 0; j < NLD; j++)
      glds16(gsrc[j] + kb, dstb + ldst[j]);
  };
  auto RD_B = [&](const char* buf) {
#pragma unroll
    for (int n = 0; n < 4; n++) {
      int row = wn * 64 + n * 16 + lr;
      bhF[n] = *(const f16x8*)(buf + BOFF + row * 64 + lkbs);
      if constexpr (NPASS == 3)
        blF[n] = *(const f16x8*)(buf + BOFF + 16384 + row * 64 + lkbs);
    }
  };
  auto RD_A = [&](const char* buf, int p, f16x8* d) {
#pragma unroll
    for (int i = 0; i < 2; i++) {
      int row = wm * 128 + (2 * p + i) * 16 + lr;
      d[i] = *(const f16x8*)(buf + row * 64 + lkbs);
      if constexpr (NPASS == 3)
        d[2 + i] = *(const f16x8*)(buf + 16384 + row * 64 + lkbs);
    }
  };

  // prologue: tiles 0 and 1 staged; wait tile 0 landed (counted)
  STAGE(0, 0);
  STAGE(1, 1);
  DP_VMCNT_P();
  DP_BAR();

  for (int kt = 0; kt < NT; kt++) {
    const char* buf = (const char*)smem_raw + (kt & 1) * BUFB;
    RD_B(buf);
    RD_A(buf, 0, aA);
    RD_A(buf, 1, aB);
    DP_LGKM_P();                 // B + A-pair0 in regs (A-pair1 in flight)
    DP_QUAD(aA, 0);
    RD_A(buf, 2, aA);
    DP_LGKM_P();                 // A-pair1 ready
    DP_QUAD(aB, 1);
    RD_A(buf, 3, aB);
    DP_LGKM_P();                 // A-pair2 ready
    DP_QUAD(aA, 2);
    DP_LGKM_0();                 // all reads of tile kt done (this wave)
    DP_BAR();                    // ... and block-wide -> safe to overwrite
    if (kt + 2 < NT) {
      STAGE(kt + 2, kt & 1);     // into the buffer we just finished reading
      DP_QUAD(aB, 3);
      DP_VMCNT_P();              // tile kt+1 landed; kt+2 stays in flight
    } else {
      DP_QUAD(aB, 3);
      DP_VMCNT_0();              // epilogue drain
    }
    DP_BAR();                    // publish buf (kt+1)&1
  }

  // epilogue: C write
#pragma unroll
  for (int mi = 0; mi < 8; mi++) {
    int row = m0 + wm * 128 + mi * 16 + ((lane >> 4) << 2);
#pragma unroll
    for (int n = 0; n < 4; n++) {
      int col = n0 + wn * 64 + n * 16 + (lane & 15);
#pragma unroll
      for (int r = 0; r < 4; r++) {
        if constexpr (OUT_HALF)
          Ch[(size_t)(row + r) * N + col] = (_Float16)acc[mi][n][r];
        else
          Cf[(size_t)(row + r) * N + col] = acc[mi][n][r];
      }
    }
  }
}
#undef DP_LGKM_P
#undef DP_LGKM_0
#undef DP_VMCNT_P
#undef DP_VMCNT_0
#undef DP_BAR
#undef DP_QUAD

// single-GEMM wrapper (O-GEMM + standalone use)
template <int NPASS, int OUT_HALF>
__global__ __launch_bounds__(512, 1) void gemm_dp(
    const _Float16* __restrict__ Ahi, const _Float16* __restrict__ Alo,
    const _Float16* __restrict__ Bhi, const _Float16* __restrict__ Blo,
    float* __restrict__ Cf, _Float16* __restrict__ Ch,
    int M, int N, int Kd) {
  extern __shared__ char smem_raw[];
  gemm_body<NPASS, OUT_HALF>(blockIdx.x, smem_raw, Ahi, Alo, Bhi, Blo,
                             Cf, Ch, M, N, Kd);
}

// merged Q+K+V projection GEMMs: one dispatch, 1536 blocks.
// Blocks [0,512)=Q (NPASS3), [512,1024)=K (NPASS3), [1024,1536)=V (NPASS1).
// Uniform top-level branch; removes 2 dispatch gaps and packs the tails.
__global__ __launch_bounds__(512, 1) void gemm_qkv(
    const _Float16* __restrict__ qh, const _Float16* __restrict__ ql,
    const _Float16* __restrict__ kh, const _Float16* __restrict__ kl,
    const _Float16* __restrict__ vh,
    const _Float16* __restrict__ wqh, const _Float16* __restrict__ wql,
    const _Float16* __restrict__ wkh, const _Float16* __restrict__ wkl,
    const _Float16* __restrict__ wvh,
    float* __restrict__ Qbuf, float* __restrict__ Kbuf,
    _Float16* __restrict__ Vbuf) {
  extern __shared__ char smem_raw[];
  const int bx = blockIdx.x;
  if (bx < 512)
    gemm_body<3, 0>(bx, smem_raw, qh, ql, wqh, wql, Qbuf, nullptr,
                    MROWS, DMODEL, DMODEL);
  else if (bx < 1024)
    gemm_body<3, 0>(bx - 512, smem_raw, kh, kl, wkh, wkl, Kbuf, nullptr,
                    MROWS, DMODEL, DMODEL);
  else
    gemm_body<1, 1>(bx - 1024, smem_raw, vh, nullptr, wvh, nullptr,
                    nullptr, Vbuf, MROWS, DMODEL, DMODEL);
}

// ---------------- fallback 128x128 2-phase GEMM (proven) -----------------
template <int NPASS, int OUT_HALF>
__global__ __launch_bounds__(256) void gemm_f16(
    const _Float16* __restrict__ Ahi, const _Float16* __restrict__ Alo,
    const _Float16* __restrict__ Bhi, const _Float16* __restrict__ Blo,
    float* __restrict__ Cf, _Float16* __restrict__ Ch,
    int M, int N, int Kd) {
  constexpr int TILE = 128 * 32;
  __shared__ _Float16 lds[(NPASS == 3 ? 4 : 2) * TILE];
  _Float16* sAh = lds;
  _Float16* sBh = lds + (NPASS == 3 ? 2 : 1) * TILE;
  _Float16* sAl = lds + TILE;
  _Float16* sBl = lds + 3 * TILE;

  const int t = threadIdx.x;
  const int lane = t & 63, wid = t >> 6;
  const int wm = wid >> 1, wn = wid & 1;
  const int lr = lane & 15, lk = (lane >> 4) * 8;

  const int mtiles = M >> 7, ntiles = N >> 7;
  const int nwg = mtiles * ntiles;
  const int qq = nwg >> 3;
  const int v = (blockIdx.x & 7) * qq + (blockIdx.x >> 3);
  const int mx = v / ntiles, ny = v % ntiles;
  const int m0 = mx * 128, n0 = ny * 128;

  f32x4 acc[4][4] = {};

  for (int k0 = 0; k0 < Kd; k0 += 32) {
#pragma unroll
    for (int i = 0; i < 2; i++) {
      int slot = t + i * 256;
      int row = slot >> 2, kc = (slot & 3) * 8;
      glds16(Ahi + (size_t)(m0 + row) * Kd + k0 + kc, sAh + slot * 8);
      glds16(Bhi + (size_t)(n0 + row) * Kd + k0 + kc, sBh + slot * 8);
      if (NPASS == 3) {
        glds16(Alo + (size_t)(m0 + row) * Kd + k0 + kc, sAl + slot * 8);
        glds16(Blo + (size_t)(n0 + row) * Kd + k0 + kc, sBl + slot * 8);
      }
    }
    __syncthreads();

    f16x8 ah[4], bh[4], al[4], bl[4];
#pragma unroll
    for (int f = 0; f < 4; f++) {
      ah[f] = *(const f16x8*)&sAh[(wm * 64 + f * 16 + lr) * 32 + lk];
      bh[f] = *(const f16x8*)&sBh[(wn * 64 + f * 16 + lr) * 32 + lk];
      if (NPASS == 3) {
        al[f] = *(const f16x8*)&sAl[(wm * 64 + f * 16 + lr) * 32 + lk];
        bl[f] = *(const f16x8*)&sBl[(wn * 64 + f * 16 + lr) * 32 + lk];
      }
    }
#pragma unroll
    for (int i = 0; i < 4; i++)
#pragma unroll
      for (int j = 0; j < 4; j++) {
        acc[i][j] = __builtin_amdgcn_mfma_f32_16x16x32_f16(ah[i], bh[j], acc[i][j], 0, 0, 0);
        if (NPASS == 3) {
          acc[i][j] = __builtin_amdgcn_mfma_f32_16x16x32_f16(ah[i], bl[j], acc[i][j], 0, 0, 0);
          acc[i][j] = __builtin_amdgcn_mfma_f32_16x16x32_f16(al[i], bh[j], acc[i][j], 0, 0, 0);
        }
      }
    __syncthreads();
  }

#pragma unroll
  for (int i = 0; i < 4; i++) {
    int row = m0 + wm * 64 + i * 16 + (lane >> 4) * 4;
#pragma unroll
    for (int j = 0; j < 4; j++) {
      int col = n0 + wn * 64 + j * 16 + (lane & 15);
#pragma unroll
      for (int r = 0; r < 4; r++) {
        if (OUT_HALF)
          Ch[(size_t)(row + r) * N + col] = (_Float16)acc[i][j][r];
        else
          Cf[(size_t)(row + r) * N + col] = acc[i][j][r];
      }
    }
  }
}

// -------- per-position head attention: 1 block (256 thr) per (b,s) -------
__global__ __launch_bounds__(256) void attn_kernel(
    const float* __restrict__ Q, const float* __restrict__ K,
    const _Float16* __restrict__ V, const float* __restrict__ mask,
    const float* __restrict__ rsQ, const float* __restrict__ rsK,
    float* __restrict__ wout, _Float16* __restrict__ aout) {
  __shared__ float lq[16][132], lkk[16][132], lv[16][132];
  __shared__ float lw[16][17];
  const int pos = blockIdx.x;
  const int t = threadIdx.x;
  const int h = t >> 4, j = t & 15;
  const size_t rowbase = (size_t)pos * DMODEL + h * DHEAD;

  const float iq = 1.f / (rsQ[(size_t)pos * NHEAD + h] + 1e-6f);
  const float ik = 1.f / (rsK[(size_t)pos * NHEAD + h] + 1e-6f);

  {
    const int dlo = 4 * j, dhi = 64 + 4 * j;
    float4 q0 = *(const float4*)&Q[rowbase + dlo];
    float4 q1 = *(const float4*)&Q[rowbase + dhi];
    q0.x *= iq; q0.y *= iq; q0.z *= iq; q0.w *= iq;
    q1.x *= iq; q1.y *= iq; q1.z *= iq; q1.w *= iq;
    *(float4*)&lq[h][dlo] = q0;
    *(float4*)&lq[h][dhi] = q1;
    float4 k0 = *(const float4*)&K[rowbase + dlo];
    float4 k1 = *(const float4*)&K[rowbase + dhi];
    k0.x *= ik; k0.y *= ik; k0.z *= ik; k0.w *= ik;
    k1.x *= ik; k1.y *= ik; k1.z *= ik; k1.w *= ik;
    *(float4*)&lkk[h][dlo] = k0;
    *(float4*)&lkk[h][dhi] = k1;
    f16x4 v0 = *(const f16x4*)&V[rowbase + dlo];
    f16x4 v1 = *(const f16x4*)&V[rowbase + dhi];
    float4 vf0 = {(float)v0[0], (float)v0[1], (float)v0[2], (float)v0[3]};
    float4 vf1 = {(float)v1[0], (float)v1[1], (float)v1[2], (float)v1[3]};
    *(float4*)&lv[h][dlo] = vf0;
    *(float4*)&lv[h][dhi] = vf1;
  }
  __syncthreads();

  const float4* qr = (const float4*)&lq[h][0];
  const float4* kr = (const float4*)&lkk[j][0];
  float dot = 0.f;
#pragma unroll
  for (int d4 = 0; d4 < 32; d4++) {
    float4 a = qr[d4], b = kr[d4];
    dot = fmaf(a.x, b.x, dot); dot = fmaf(a.y, b.y, dot);
    dot = fmaf(a.z, b.z, dot); dot = fmaf(a.w, b.w, dot);
  }
  float mk = mask[(size_t)pos * 256 + t];
  float x = (dot - 1e9f * mk) * 0.08838834764831845f;  // 1/sqrt(128)
  float mx = x;
#pragma unroll
  for (int m = 1; m < 16; m <<= 1) mx = fmaxf(mx, __shfl_xor(mx, m, 64));
  float e = expf(x - mx);
  float den = e;
#pragma unroll
  for (int m = 1; m < 16; m <<= 1) den += __shfl_xor(den, m, 64);
  float w = e / den;
  wout[(size_t)pos * 256 + t] = w;
  lw[h][j] = w;
  __syncthreads();

  float wreg[16];
#pragma unroll
  for (int k2 = 0; k2 < 16; k2++) wreg[k2] = lw[h][k2];
  float4 a0 = {0.f, 0.f, 0.f, 0.f}, a1 = {0.f, 0.f, 0.f, 0.f};
  const int dlo = 4 * j, dhi = 64 + 4 * j;
#pragma unroll
  for (int k2 = 0; k2 < 16; k2++) {
    float4 v0 = *(const float4*)&lv[k2][dlo];
    float4 v1 = *(const float4*)&lv[k2][dhi];
    float wk = wreg[k2];
    a0.x = fmaf(wk, v0.x, a0.x); a0.y = fmaf(wk, v0.y, a0.y);
    a0.z = fmaf(wk, v0.z, a0.z); a0.w = fmaf(wk, v0.w, a0.w);
    a1.x = fmaf(wk, v1.x, a1.x); a1.y = fmaf(wk, v1.y, a1.y);
    a1.z = fmaf(wk, v1.z, a1.z); a1.w = fmaf(wk, v1.w, a1.w);
  }
  f16x4 o0, o1;
  o0[0] = (_Float16)a0.x; o0[1] = (_Float16)a0.y;
  o0[2] = (_Float16)a0.z; o0[3] = (_Float16)a0.w;
  o1[0] = (_Float16)a1.x; o1[1] = (_Float16)a1.y;
  o1[2] = (_Float16)a1.z; o1[3] = (_Float16)a1.w;
  *(f16x4*)&aout[rowbase + dlo] = o0;
  *(f16x4*)&aout[rowbase + dhi] = o1;
}

// -------------------------------------------------------------------------
extern "C" void kernel_launch(void* const* d_in, const int* in_sizes, int n_in,
                              void* d_out, int out_size, void* d_ws, size_t ws_size,
                              hipStream_t stream) {
  const float* query = (const float*)d_in[0];
  const float* key   = (const float*)d_in[1];
  const float* value = (const float*)d_in[2];
  const float* mask  = (const float*)d_in[3];
  const float* Wq = (const float*)d_in[4];
  const float* Wk = (const float*)d_in[5];
  const float* Wv = (const float*)d_in[6];
  const float* Wo = (const float*)d_in[7];

  float* out  = (float*)d_out;                       // [16384, 2048] fp32
  float* wout = out + (size_t)MROWS * DMODEL;        // [16384, 256] fp32

  const size_t SZ_HALF = (size_t)MROWS * DMODEL * 2; // 67.1 MB
  const size_t SZ_F32  = (size_t)MROWS * DMODEL * 4; // 134.2 MB
  const size_t SZ_W    = (size_t)DMODEL * DMODEL * 2;// 8.4 MB
  const size_t SZ_CS   = (size_t)DMODEL * NHEAD * 4; // 128 KB (fp32)
  const size_t SZ_RS   = (size_t)MROWS * NHEAD * 4;  // 1 MB

  const int n8 = MROWS * DMODEL / 8;
  const int ggrid = (MROWS / 128) * (DMODEL / 128);  // fallback grid
  dim3 tgrid4(DMODEL / 32, DMODEL / 32, 4);
  dim3 tgrid(DMODEL / 32, DMODEL / 32);
  dim3 tblk(32, 8);
  dim3 prepgrid(MROWS / 8, 3);
  dim3 rsgrid(MROWS / 8, 2);
  const int dpgrid = (MROWS / 256) * (DMODEL / 256); // 512 blocks
  float* Qbuf = out;   // Q fp32 parked in d_out, overwritten by final GEMM

  const size_t NEED_A = 5 * SZ_HALF + SZ_F32 + 6 * SZ_W + 2 * SZ_CS + 2 * SZ_RS;
  const size_t NEED_B = 3 * SZ_HALF + SZ_F32 + 2 * SZ_W + 2 * SZ_CS + 2 * SZ_RS;
  char* ws = (char*)d_ws;

  if (ws_size >= NEED_A) {
    size_t off = 0;
    _Float16* qh = (_Float16*)(ws + off); off += SZ_HALF;
    _Float16* ql = (_Float16*)(ws + off); off += SZ_HALF;
    _Float16* kh = (_Float16*)(ws + off); off += SZ_HALF;
    _Float16* kl = (_Float16*)(ws + off); off += SZ_HALF;
    _Float16* vh = (_Float16*)(ws + off); off += SZ_HALF;
    float*  Kbuf = (float*)   (ws + off); off += SZ_F32;
    _Float16* wqh = (_Float16*)(ws + off); off += SZ_W;
    _Float16* wql = (_Float16*)(ws + off); off += SZ_W;
    _Float16* wkh = (_Float16*)(ws + off); off += SZ_W;
    _Float16* wkl = (_Float16*)(ws + off); off += SZ_W;
    _Float16* wvh = (_Float16*)(ws + off); off += SZ_W;
    _Float16* woh = (_Float16*)(ws + off); off += SZ_W;
    float* CSq = (float*)(ws + off); off += SZ_CS;
    float* CSk = (float*)(ws + off); off += SZ_CS;
    float* rsQ = (float*)(ws + off); off += SZ_RS;
    float* rsK = (float*)(ws + off); off += SZ_RS;
    _Float16* Vbuf   = qh;   // qh dead after Q-GEMM
    _Float16* attn16 = ql;   // ql dead after Q-GEMM

    colsum2<<<dim3(DMODEL, 2), 256, 0, stream>>>(Wq, Wk, CSq, CSk);
    prep_qkv<<<prepgrid, 256, 0, stream>>>(query, key, value, CSq, CSk,
                                           qh, ql, kh, kl, vh, rsQ, rsK);
    transpose_all<<<tgrid4, tblk, 0, stream>>>(Wq, Wk, Wv, Wo, wqh, wql, wkh, wkl, wvh, woh);
    gemm_qkv<<<1536, 512, 131072, stream>>>(qh, ql, kh, kl, vh,
                                            wqh, wql, wkh, wkl, wvh,
                                            Qbuf, Kbuf, Vbuf);
    attn_kernel<<<MROWS, 256, 0, stream>>>(Qbuf, Kbuf, Vbuf, mask, rsQ, rsK, wout, attn16);
    gemm_dp<1, 0><<<dpgrid, 512, 65536, stream>>>(attn16, nullptr, woh, nullptr, out, nullptr, MROWS, DMODEL, DMODEL);
    return;
  }

  if (ws_size < NEED_B) return;  // workspace too small — fail visibly

  // Fallback: sequential-reuse layout with proven 2-phase GEMM
  _Float16* a_hi  = (_Float16*)ws;
  _Float16* a_lo  = (_Float16*)(ws + SZ_HALF);
  float*    Kbuf  = (float*)   (ws + 2 * SZ_HALF);
  _Float16* Vbuf  = (_Float16*)(ws + 2 * SZ_HALF + SZ_F32);
  _Float16* wT_hi = (_Float16*)(ws + 3 * SZ_HALF + SZ_F32);
  _Float16* wT_lo = (_Float16*)(ws + 3 * SZ_HALF + SZ_F32 + SZ_W);
  float*    CSq   = (float*)   (ws + 3 * SZ_HALF + SZ_F32 + 2 * SZ_W);
  float*    CSk   = (float*)   (ws + 3 * SZ_HALF + SZ_F32 + 2 * SZ_W + SZ_CS);
  float*    rsQ   = (float*)   (ws + 3 * SZ_HALF + SZ_F32 + 2 * SZ_W + 2 * SZ_CS);
  float*    rsK   = (float*)   (ws + 3 * SZ_HALF + SZ_F32 + 2 * SZ_W + 2 * SZ_CS + SZ_RS);
  _Float16* attn16 = a_hi;

  colsum_f64<<<DMODEL, 256, 0, stream>>>(Wq, CSq);
  colsum_f64<<<DMODEL, 256, 0, stream>>>(Wk, CSk);
  rowsum_v3<<<rsgrid, 256, 0, stream>>>(query, key, CSq, CSk, rsQ, rsK);

  split_f32_f16<<<4096, 256, 0, stream>>>(query, a_hi, a_lo, n8);
  transpose_split<<<tgrid, tblk, 0, stream>>>(Wq, wT_hi, wT_lo);
  gemm_f16<3, 0><<<ggrid, 256, 0, stream>>>(a_hi, a_lo, wT_hi, wT_lo, Qbuf, nullptr, MROWS, DMODEL, DMODEL);
  split_f32_f16<<<4096, 256, 0, stream>>>(key, a_hi, a_lo, n8);
  transpose_split<<<tgrid, tblk, 0, stream>>>(Wk, wT_hi, wT_lo);
  gemm_f16<3, 0><<<ggrid, 256, 0, stream>>>(a_hi, a_lo, wT_hi, wT_lo, Kbuf, nullptr, MROWS, DMODEL, DMODEL);
  split_f32_f16<<<4096, 256, 0, stream>>>(value, a_hi, nullptr, n8);
  transpose_split<<<tgrid, tblk, 0, stream>>>(Wv, wT_hi, nullptr);
  gemm_f16<1, 1><<<ggrid, 256, 0, stream>>>(a_hi, nullptr, wT_hi, nullptr, nullptr, Vbuf, MROWS, DMODEL, DMODEL);
  attn_kernel<<<MROWS, 256, 0, stream>>>(Qbuf, Kbuf, Vbuf, mask, rsQ, rsK, wout, attn16);
  transpose_split<<<tgrid, tblk, 0, stream>>>(Wo, wT_hi, nullptr);
  gemm_f16<1, 0><<<ggrid, 256, 0, stream>>>(attn16, nullptr, wT_hi, nullptr, out, nullptr, MROWS, DMODEL, DMODEL);
}

// Round 15
// 1433.428 us; speedup vs baseline: 1.3519x; 1.0007x over previous
//
#include <hip/hip_runtime.h>
#include <hip/hip_fp16.h>

#define NHEAD 16
#define DHEAD 128
#define DMODEL 2048
#define SEQ 4096
#define BATCH 4
#define MROWS (BATCH*SEQ)   // 16384

typedef _Float16 f16x8 __attribute__((ext_vector_type(8)));
typedef _Float16 f16x4 __attribute__((ext_vector_type(4)));
typedef float f32x4 __attribute__((ext_vector_type(4)));

// ---------------- fp32 -> fp16 (hi, lo) split, 8 elems/thread ------------
__device__ inline void split8(const float* __restrict__ x, _Float16* __restrict__ hi,
                              _Float16* __restrict__ lo, int i8) {
  float4 v0 = ((const float4*)x)[2 * i8];
  float4 v1 = ((const float4*)x)[2 * i8 + 1];
  f16x8 h, l;
  h[0] = (_Float16)v0.x; h[1] = (_Float16)v0.y;
  h[2] = (_Float16)v0.z; h[3] = (_Float16)v0.w;
  h[4] = (_Float16)v1.x; h[5] = (_Float16)v1.y;
  h[6] = (_Float16)v1.z; h[7] = (_Float16)v1.w;
  ((f16x8*)hi)[i8] = h;
  if (lo) {
    l[0] = (_Float16)(v0.x - (float)h[0]);
    l[1] = (_Float16)(v0.y - (float)h[1]);
    l[2] = (_Float16)(v0.z - (float)h[2]);
    l[3] = (_Float16)(v0.w - (float)h[3]);
    l[4] = (_Float16)(v1.x - (float)h[4]);
    l[5] = (_Float16)(v1.y - (float)h[5]);
    l[6] = (_Float16)(v1.z - (float)h[6]);
    l[7] = (_Float16)(v1.w - (float)h[7]);
    ((f16x8*)lo)[i8] = l;
  }
}

// one matrix per launch (fallback path)
__global__ __launch_bounds__(256) void split_f32_f16(
    const float* __restrict__ x, _Float16* __restrict__ hi,
    _Float16* __restrict__ lo, int n8) {
  int i = blockIdx.x * blockDim.x + threadIdx.x;
  int stride = gridDim.x * blockDim.x;
  for (; i < n8; i += stride) split8(x, hi, lo, i);
}

// ------------- weight transpose + split: W[K][N] -> WT[N][K] f16 ---------
__device__ inline void transpose_body(const float* __restrict__ W,
                                      _Float16* __restrict__ hi,
                                      _Float16* __restrict__ lo,
                                      int bx, int by, int tx, int ty) {
  __shared__ float tile[32][33];
  int c = bx * 32 + tx;
  for (int r0 = 0; r0 < 32; r0 += 8) {
    int r = by * 32 + ty + r0;
    tile[ty + r0][tx] = W[(size_t)r * DMODEL + c];
  }
  __syncthreads();
  for (int r0 = 0; r0 < 32; r0 += 8) {
    int n = bx * 32 + ty + r0;             // WT row = original col
    int k = by * 32 + tx;                  // WT col = original row
    float v = tile[tx][ty + r0];           // = W[k][n]
    _Float16 h = (_Float16)v;
    hi[(size_t)n * DMODEL + k] = h;
    if (lo) lo[(size_t)n * DMODEL + k] = (_Float16)(v - (float)h);
  }
}

__global__ __launch_bounds__(256) void transpose_split(
    const float* __restrict__ W, _Float16* __restrict__ hi,
    _Float16* __restrict__ lo) {
  transpose_body(W, hi, lo, blockIdx.x, blockIdx.y, threadIdx.x, threadIdx.y);
}

// ---- colsum body: CS_T[h][k] = sum_d W[k][h*128+d], fp64 accumulate -----
__device__ inline void colsum_body(const float* __restrict__ W,
                                   float* __restrict__ CS, int k, int t) {
  const int h = t >> 4, s = t & 15;
  double acc = 0.0;
  const float* p = W + (size_t)k * DMODEL + h * DHEAD + s * 8;
#pragma unroll
  for (int i = 0; i < 8; i++) acc += (double)p[i];
#pragma unroll
  for (int m = 1; m < 16; m <<= 1) acc += __shfl_xor(acc, m, 64);
  if (s == 0) CS[(size_t)h * DMODEL + k] = (float)acc;
}

// fallback single-matrix colsum
__global__ __launch_bounds__(256) void colsum_f64(
    const float* __restrict__ W, float* __restrict__ CS) {
  colsum_body(W, CS, blockIdx.x, threadIdx.x);
}

// ---- merged weights prep: 4 transposes + 2 colsums in ONE dispatch ------
// z=0..3: transpose_body for Wq/Wk/Wv/Wo (grid 64x64 tiles).
// z=4: 4096 colsum blocks (id = by*64+bx; bit 11 selects Wq/Wk).
__global__ __launch_bounds__(256) void weights_prep(
    const float* __restrict__ Wq, const float* __restrict__ Wk,
    const float* __restrict__ Wv, const float* __restrict__ Wo,
    _Float16* __restrict__ qh, _Float16* __restrict__ ql,
    _Float16* __restrict__ kh, _Float16* __restrict__ kl,
    _Float16* __restrict__ vh, _Float16* __restrict__ oh,
    float* __restrict__ CSq, float* __restrict__ CSk) {
  const int z = blockIdx.z;
  const int t = threadIdx.y * 32 + threadIdx.x;
  if (z == 4) {
    int id = blockIdx.y * 64 + blockIdx.x;       // 0..4095
    const float* W = (id & 2048) ? Wk : Wq;
    float* CS = (id & 2048) ? CSk : CSq;
    colsum_body(W, CS, id & 2047, t);
    return;
  }
  const float* W; _Float16* hi; _Float16* lo;
  switch (z) {
    case 0:  W = Wq; hi = qh; lo = ql;      break;
    case 1:  W = Wk; hi = kh; lo = kl;      break;
    case 2:  W = Wv; hi = vh; lo = nullptr; break;
    default: W = Wo; hi = oh; lo = nullptr; break;
  }
  transpose_body(W, hi, lo, blockIdx.x, blockIdx.y, threadIdx.x, threadIdx.y);
}

// ---- fused activation prep: fp16 split + exact fp64 per-head rowsums ----
__global__ __launch_bounds__(256) void prep_qkv(
    const float* __restrict__ q, const float* __restrict__ k,
    const float* __restrict__ v,
    const float* __restrict__ CSq, const float* __restrict__ CSk,
    _Float16* __restrict__ qh, _Float16* __restrict__ ql,
    _Float16* __restrict__ kh, _Float16* __restrict__ kl,
    _Float16* __restrict__ vh,
    float* __restrict__ rsQ, float* __restrict__ rsK) {
  const float* X; const float* CS; float* rs;
  _Float16* hi; _Float16* lo;
  if (blockIdx.y == 0)      { X = q; CS = CSq; rs = rsQ; hi = qh; lo = ql; }
  else if (blockIdx.y == 1) { X = k; CS = CSk; rs = rsK; hi = kh; lo = kl; }
  else                      { X = v; CS = nullptr; rs = nullptr; hi = vh; lo = nullptr; }
  const int t = threadIdx.x;
  const int lane = t & 63, w = t >> 6;
  const int row0 = blockIdx.x * 8 + w * 2;     // 2 rows per wave

  const float4* x0 = (const float4*)(X + ((size_t)row0 << 11));
  const float4* x1 = (const float4*)(X + ((size_t)(row0 + 1) << 11));
  float4 xa[8], xb[8];
#pragma unroll
  for (int i = 0; i < 8; i++) {
    xa[i] = x0[i * 64 + lane];
    xb[i] = x1[i * 64 + lane];
  }

  f16x4* hi4 = (f16x4*)hi;
  f16x4* lo4 = (f16x4*)lo;
  const size_t rb0 = (size_t)row0 << 9;        // row0 * 2048/4
  const size_t rb1 = (size_t)(row0 + 1) << 9;
#pragma unroll
  for (int i = 0; i < 8; i++) {
    int c = i * 64 + lane;
    float4 a = xa[i], b = xb[i];
    f16x4 ha, hb;
    ha[0] = (_Float16)a.x; ha[1] = (_Float16)a.y;
    ha[2] = (_Float16)a.z; ha[3] = (_Float16)a.w;
    hb[0] = (_Float16)b.x; hb[1] = (_Float16)b.y;
    hb[2] = (_Float16)b.z; hb[3] = (_Float16)b.w;
    hi4[rb0 + c] = ha;
    hi4[rb1 + c] = hb;
    if (lo) {
      f16x4 la, lb;
      la[0] = (_Float16)(a.x - (float)ha[0]);
      la[1] = (_Float16)(a.y - (float)ha[1]);
      la[2] = (_Float16)(a.z - (float)ha[2]);
      la[3] = (_Float16)(a.w - (float)ha[3]);
      lb[0] = (_Float16)(b.x - (float)hb[0]);
      lb[1] = (_Float16)(b.y - (float)hb[1]);
      lb[2] = (_Float16)(b.z - (float)hb[2]);
      lb[3] = (_Float16)(b.w - (float)hb[3]);
      lo4[rb0 + c] = la;
      lo4[rb1 + c] = lb;
    }
  }

  if (CS) {
    const float4* cs4 = (const float4*)CS;
    for (int h = 0; h < 16; h++) {
      double a0 = 0.0, a1 = 0.0;
#pragma unroll
      for (int i = 0; i < 8; i++) {
        float4 cv = cs4[h * 512 + i * 64 + lane];
        a0 += (double)xa[i].x * (double)cv.x + (double)xa[i].y * (double)cv.y
            + (double)xa[i].z * (double)cv.z + (double)xa[i].w * (double)cv.w;
        a1 += (double)xb[i].x * (double)cv.x + (double)xb[i].y * (double)cv.y
            + (double)xb[i].z * (double)cv.z + (double)xb[i].w * (double)cv.w;
      }
#pragma unroll
      for (int m = 1; m < 64; m <<= 1) {
        a0 += __shfl_xor(a0, m, 64);
        a1 += __shfl_xor(a1, m, 64);
      }
      if (lane == 0) {
        rs[(size_t)row0 * NHEAD + h]       = (float)a0;
        rs[(size_t)(row0 + 1) * NHEAD + h] = (float)a1;
      }
    }
  }
}

// ---- exact per-head row sums, v3 (fallback path) ------------------------
__global__ __launch_bounds__(256) void rowsum_v3(
    const float* __restrict__ q, const float* __restrict__ k,
    const float* __restrict__ CSq, const float* __restrict__ CSk,
    float* __restrict__ rsQ, float* __restrict__ rsK) {
  const float* X;  const float* CS;  float* rs;
  if (blockIdx.y == 0) { X = q; CS = CSq; rs = rsQ; }
  else                 { X = k; CS = CSk; rs = rsK; }
  const int t = threadIdx.x;
  const int lane = t & 63, w = t >> 6;
  const int row0 = blockIdx.x * 8 + w * 2;     // 2 rows per wave

  const float4* x0 = (const float4*)(X + ((size_t)row0 << 11));
  const float4* x1 = (const float4*)(X + ((size_t)(row0 + 1) << 11));
  float4 xa[8], xb[8];
#pragma unroll
  for (int i = 0; i < 8; i++) {
    xa[i] = x0[i * 64 + lane];
    xb[i] = x1[i * 64 + lane];
  }
  const float4* cs4 = (const float4*)CS;

  for (int h = 0; h < 16; h++) {
    double a0 = 0.0, a1 = 0.0;
#pragma unroll
    for (int i = 0; i < 8; i++) {
      float4 cv = cs4[h * 512 + i * 64 + lane];
      a0 += (double)xa[i].x * (double)cv.x + (double)xa[i].y * (double)cv.y
          + (double)xa[i].z * (double)cv.z + (double)xa[i].w * (double)cv.w;
      a1 += (double)xb[i].x * (double)cv.x + (double)xb[i].y * (double)cv.y
          + (double)xb[i].z * (double)cv.z + (double)xb[i].w * (double)cv.w;
    }
#pragma unroll
    for (int m = 1; m < 64; m <<= 1) {
      a0 += __shfl_xor(a0, m, 64);
      a1 += __shfl_xor(a1, m, 64);
    }
    if (lane == 0) {
      rs[(size_t)row0 * NHEAD + h]       = (float)a0;
      rs[(size_t)(row0 + 1) * NHEAD + h] = (float)a1;
    }
  }
}

// -------------------------- async global->LDS ----------------------------
__device__ inline void glds16(const void* g, void* l) {
  __builtin_amdgcn_global_load_lds(
      (const __attribute__((address_space(1))) unsigned int*)g,
      (__attribute__((address_space(3))) unsigned int*)l, 16, 0, 0);
}

// ========== deep-pipelined 256x256 GEMM body (R10 banked schedule) =======
// Do not edit the schedule: R11's deeper rotation spilled and regressed 50%.
// acc lives in AGPRs; 120 VGPR + 128 AGPR fits 2 waves/SIMD.
#define DP_LGKM_P() do { \
  if constexpr (NPASS == 3) asm volatile("s_waitcnt lgkmcnt(4)" ::: "memory"); \
  else                      asm volatile("s_waitcnt lgkmcnt(2)" ::: "memory"); \
  __builtin_amdgcn_sched_barrier(0); } while (0)
#define DP_LGKM_0() do { \
  asm volatile("s_waitcnt lgkmcnt(0)" ::: "memory"); \
  __builtin_amdgcn_sched_barrier(0); } while (0)
#define DP_VMCNT_P() do { \
  if constexpr (NPASS == 3) asm volatile("s_waitcnt vmcnt(8)" ::: "memory"); \
  else                      asm volatile("s_waitcnt vmcnt(4)" ::: "memory"); \
  __builtin_amdgcn_sched_barrier(0); } while (0)
#define DP_VMCNT_0() do { \
  asm volatile("s_waitcnt vmcnt(0)" ::: "memory"); \
  __builtin_amdgcn_sched_barrier(0); } while (0)
#define DP_BAR() do { \
  asm volatile("" ::: "memory"); \
  __builtin_amdgcn_s_barrier(); \
  asm volatile("" ::: "memory"); } while (0)
#define DP_QUAD(AR, P) do { \
  __builtin_amdgcn_s_setprio(1); \
  _Pragma("unroll") \
  for (int i_ = 0; i_ < 2; i_++) \
    _Pragma("unroll") \
    for (int n_ = 0; n_ < 4; n_++) { \
      acc[2*(P)+i_][n_] = __builtin_amdgcn_mfma_f32_16x16x32_f16(AR[i_], bhF[n_], acc[2*(P)+i_][n_], 0, 0, 0); \
      if constexpr (NPASS == 3) { \
        acc[2*(P)+i_][n_] = __builtin_amdgcn_mfma_f32_16x16x32_f16(AR[i_], blF[n_], acc[2*(P)+i_][n_], 0, 0, 0); \
        acc[2*(P)+i_][n_] = __builtin_amdgcn_mfma_f32_16x16x32_f16(AR[2+i_], bhF[n_], acc[2*(P)+i_][n_], 0, 0, 0); \
      } \
    } \
  __builtin_amdgcn_s_setprio(0); } while (0)

template <int NPASS, int OUT_HALF>
__device__ __forceinline__ void gemm_body(
    int bid, char* smem_raw,
    const _Float16* __restrict__ Ahi, const _Float16* __restrict__ Alo,
    const _Float16* __restrict__ Bhi, const _Float16* __restrict__ Blo,
    float* __restrict__ Cf, _Float16* __restrict__ Ch,
    int M, int N, int Kd) {
  constexpr int NMAT = (NPASS == 3) ? 4 : 2;
  constexpr int NLD  = NMAT * 2;                      // glds16 per thread/tile
  constexpr int BUFB = NMAT * 16384;                  // bytes per K-tile buf
  constexpr int BOFF = (NPASS == 3) ? 32768 : 16384;  // Bhi byte offset

  const int t = threadIdx.x;
  const int lane = t & 63, wid = t >> 6;
  const int wm = wid >> 2, wn = wid & 3;              // 2 x 4 waves
  const int lr = lane & 15;
  // swizzled per-thread k-byte offset for LDS reads (row-quad = (lr>>1)&3)
  const int lkbs = (((lane >> 4) ^ ((lr >> 1) & 3)) << 4);

  // XCD-chunked bijective swizzle (nwg = 512, %8 == 0)
  const int mtiles = M >> 8, ntiles = N >> 8;
  const int nwg = mtiles * ntiles;
  const int qq = nwg >> 3;
  const int v = (bid & 7) * qq + (bid >> 3);
  const int m0 = (v / ntiles) << 8, n0 = (v % ntiles) << 8;
  const int NT = Kd >> 5;

  f32x4 acc[8][4] = {};
  f16x8 bhF[4], blF[4], aA[4], aB[4];

  // hoisted STAGE addressing: per-thread global base ptrs + LDS dest offs
  const char* gsrc[NLD];
  int ldst[NLD];
#pragma unroll
  for (int j = 0; j < NLD; j++) {
    int s = t + j * 512;                 // slot; runs never cross matrices
    int mm = s >> 10;
    int r = (s & 1023) >> 2;
    int g = s & 3;
    int gs = g ^ ((r >> 1) & 3);         // pre-swizzled source k-chunk
    const _Float16* src; int rb;
    if (mm == 0)      { src = Ahi; rb = m0 + r; }
    else if (mm == 1) { src = (NPASS == 3) ? Alo : Bhi;
                        rb = ((NPASS == 3) ? m0 : n0) + r; }
    else if (mm == 2) { src = Bhi; rb = n0 + r; }
    else              { src = Blo; rb = n0 + r; }
    gsrc[j] = (const char*)(src + (size_t)rb * Kd + gs * 8);
    ldst[j] = s * 16;
  }

  auto STAGE = [&](int kt, int c) {
    char* dstb = smem_raw + c * BUFB;
    const size_t kb = (size_t)kt << 6;   // kt*32 f16 = kt*64 bytes
#pragma unroll
    for (int j = 0; j < NLD; j++)
      glds16(gsrc[j] + kb, dstb + ldst[j]);
  };
  auto RD_B = [&](const char* buf) {
#pragma unroll
    for (int n = 0; n < 4; n++) {
      int row = wn * 64 + n * 16 + lr;
      bhF[n] = *(const f16x8*)(buf + BOFF + row * 64 + lkbs);
      if constexpr (NPASS == 3)
        blF[n] = *(const f16x8*)(buf + BOFF + 16384 + row * 64 + lkbs);
    }
  };
  auto RD_A = [&](const char* buf, int p, f16x8* d) {
#pragma unroll
    for (int i = 0; i < 2; i++) {
      int row = wm * 128 + (2 * p + i) * 16 + lr;
      d[i] = *(const f16x8*)(buf + row * 64 + lkbs);
      if constexpr (NPASS == 3)
        d[2 + i] = *(const f16x8*)(buf + 16384 + row * 64 + lkbs);
    }
  };

  // prologue: tiles 0 and 1 staged; wait tile 0 landed (counted)
  STAGE(0, 0);
  STAGE(1, 1);
  DP_VMCNT_P();
  DP_BAR();

  for (int kt = 0; kt < NT; kt++) {
    const char* buf = (const char*)smem_raw + (kt & 1) * BUFB;
    RD_B(buf);
    RD_A(buf, 0, aA);
    RD_A(buf, 1, aB);
    DP_LGKM_P();                 // B + A-pair0 in regs (A-pair1 in flight)
    DP_QUAD(aA, 0);
    RD_A(buf, 2, aA);
    DP_LGKM_P();                 // A-pair1 ready
    DP_QUAD(aB, 1);
    RD_A(buf, 3, aB);
    DP_LGKM_P();                 // A-pair2 ready
    DP_QUAD(aA, 2);
    DP_LGKM_0();                 // all reads of tile kt done (this wave)
    DP_BAR();                    // ... and block-wide -> safe to overwrite
    if (kt + 2 < NT) {
      STAGE(kt + 2, kt & 1);     // into the buffer we just finished reading
      DP_QUAD(aB, 3);
      DP_VMCNT_P();              // tile kt+1 landed; kt+2 stays in flight
    } else {
      DP_QUAD(aB, 3);
      DP_VMCNT_0();              // epilogue drain
    }
    DP_BAR();                    // publish buf (kt+1)&1
  }

  // epilogue: C write
#pragma unroll
  for (int mi = 0; mi < 8; mi++) {
    int row = m0 + wm * 128 + mi * 16 + ((lane >> 4) << 2);
#pragma unroll
    for (int n = 0; n < 4; n++) {
      int col = n0 + wn * 64 + n * 16 + (lane & 15);
#pragma unroll
      for (int r = 0; r < 4; r++) {
        if constexpr (OUT_HALF)
          Ch[(size_t)(row + r) * N + col] = (_Float16)acc[mi][n][r];
        else
          Cf[(size_t)(row + r) * N + col] = acc[mi][n][r];
      }
    }
  }
}
#undef DP_LGKM_P
#undef DP_LGKM_0
#undef DP_VMCNT_P
#undef DP_VMCNT_0
#undef DP_BAR
#undef DP_QUAD

// single-GEMM wrapper (O-GEMM + standalone use)
template <int NPASS, int OUT_HALF>
__global__ __launch_bounds__(512, 1) void gemm_dp(
    const _Float16* __restrict__ Ahi, const _Float16* __restrict__ Alo,
    const _Float16* __restrict__ Bhi, const _Float16* __restrict__ Blo,
    float* __restrict__ Cf, _Float16* __restrict__ Ch,
    int M, int N, int Kd) {
  extern __shared__ char smem_raw[];
  gemm_body<NPASS, OUT_HALF>(blockIdx.x, smem_raw, Ahi, Alo, Bhi, Blo,
                             Cf, Ch, M, N, Kd);
}

// merged Q+K+V projection GEMMs: one dispatch, 1536 blocks.
__global__ __launch_bounds__(512, 1) void gemm_qkv(
    const _Float16* __restrict__ qh, const _Float16* __restrict__ ql,
    const _Float16* __restrict__ kh, const _Float16* __restrict__ kl,
    const _Float16* __restrict__ vh,
    const _Float16* __restrict__ wqh, const _Float16* __restrict__ wql,
    const _Float16* __restrict__ wkh, const _Float16* __restrict__ wkl,
    const _Float16* __restrict__ wvh,
    float* __restrict__ Qbuf, float* __restrict__ Kbuf,
    _Float16* __restrict__ Vbuf) {
  extern __shared__ char smem_raw[];
  const int bx = blockIdx.x;
  if (bx < 512)
    gemm_body<3, 0>(bx, smem_raw, qh, ql, wqh, wql, Qbuf, nullptr,
                    MROWS, DMODEL, DMODEL);
  else if (bx < 1024)
    gemm_body<3, 0>(bx - 512, smem_raw, kh, kl, wkh, wkl, Kbuf, nullptr,
                    MROWS, DMODEL, DMODEL);
  else
    gemm_body<1, 1>(bx - 1024, smem_raw, vh, nullptr, wvh, nullptr,
                    nullptr, Vbuf, MROWS, DMODEL, DMODEL);
}

// ---------------- fallback 128x128 2-phase GEMM (proven) -----------------
template <int NPASS, int OUT_HALF>
__global__ __launch_bounds__(256) void gemm_f16(
    const _Float16* __restrict__ Ahi, const _Float16* __restrict__ Alo,
    const _Float16* __restrict__ Bhi, const _Float16* __restrict__ Blo,
    float* __restrict__ Cf, _Float16* __restrict__ Ch,
    int M, int N, int Kd) {
  constexpr int TILE = 128 * 32;
  __shared__ _Float16 lds[(NPASS == 3 ? 4 : 2) * TILE];
  _Float16* sAh = lds;
  _Float16* sBh = lds + (NPASS == 3 ? 2 : 1) * TILE;
  _Float16* sAl = lds + TILE;
  _Float16* sBl = lds + 3 * TILE;

  const int t = threadIdx.x;
  const int lane = t & 63, wid = t >> 6;
  const int wm = wid >> 1, wn = wid & 1;
  const int lr = lane & 15, lk = (lane >> 4) * 8;

  const int mtiles = M >> 7, ntiles = N >> 7;
  const int nwg = mtiles * ntiles;
  const int qq = nwg >> 3;
  const int v = (blockIdx.x & 7) * qq + (blockIdx.x >> 3);
  const int mx = v / ntiles, ny = v % ntiles;
  const int m0 = mx * 128, n0 = ny * 128;

  f32x4 acc[4][4] = {};

  for (int k0 = 0; k0 < Kd; k0 += 32) {
#pragma unroll
    for (int i = 0; i < 2; i++) {
      int slot = t + i * 256;
      int row = slot >> 2, kc = (slot & 3) * 8;
      glds16(Ahi + (size_t)(m0 + row) * Kd + k0 + kc, sAh + slot * 8);
      glds16(Bhi + (size_t)(n0 + row) * Kd + k0 + kc, sBh + slot * 8);
      if (NPASS == 3) {
        glds16(Alo + (size_t)(m0 + row) * Kd + k0 + kc, sAl + slot * 8);
        glds16(Blo + (size_t)(n0 + row) * Kd + k0 + kc, sBl + slot * 8);
      }
    }
    __syncthreads();

    f16x8 ah[4], bh[4], al[4], bl[4];
#pragma unroll
    for (int f = 0; f < 4; f++) {
      ah[f] = *(const f16x8*)&sAh[(wm * 64 + f * 16 + lr) * 32 + lk];
      bh[f] = *(const f16x8*)&sBh[(wn * 64 + f * 16 + lr) * 32 + lk];
      if (NPASS == 3) {
        al[f] = *(const f16x8*)&sAl[(wm * 64 + f * 16 + lr) * 32 + lk];
        bl[f] = *(const f16x8*)&sBl[(wn * 64 + f * 16 + lr) * 32 + lk];
      }
    }
#pragma unroll
    for (int i = 0; i < 4; i++)
#pragma unroll
      for (int j = 0; j < 4; j++) {
        acc[i][j] = __builtin_amdgcn_mfma_f32_16x16x32_f16(ah[i], bh[j], acc[i][j], 0, 0, 0);
        if (NPASS == 3) {
          acc[i][j] = __builtin_amdgcn_mfma_f32_16x16x32_f16(ah[i], bl[j], acc[i][j], 0, 0, 0);
          acc[i][j] = __builtin_amdgcn_mfma_f32_16x16x32_f16(al[i], bh[j], acc[i][j], 0, 0, 0);
        }
      }
    __syncthreads();
  }

#pragma unroll
  for (int i = 0; i < 4; i++) {
    int row = m0 + wm * 64 + i * 16 + (lane >> 4) * 4;
#pragma unroll
    for (int j = 0; j < 4; j++) {
      int col = n0 + wn * 64 + j * 16 + (lane & 15);
#pragma unroll
      for (int r = 0; r < 4; r++) {
        if (OUT_HALF)
          Ch[(size_t)(row + r) * N + col] = (_Float16)acc[i][j][r];
        else
          Cf[(size_t)(row + r) * N + col] = acc[i][j][r];
      }
    }
  }
}

// -------- per-position head attention: 1 block (256 thr) per (b,s) -------
__global__ __launch_bounds__(256) void attn_kernel(
    const float* __restrict__ Q, const float* __restrict__ K,
    const _Float16* __restrict__ V, const float* __restrict__ mask,
    const float* __restrict__ rsQ, const float* __restrict__ rsK,
    float* __restrict__ wout, _Float16* __restrict__ aout) {
  __shared__ float lq[16][132], lkk[16][132], lv[16][132];
  __shared__ float lw[16][17];
  const int pos = blockIdx.x;
  const int t = threadIdx.x;
  const int h = t >> 4, j = t & 15;
  const size_t rowbase = (size_t)pos * DMODEL + h * DHEAD;

  const float iq = 1.f / (rsQ[(size_t)pos * NHEAD + h] + 1e-6f);
  const float ik = 1.f / (rsK[(size_t)pos * NHEAD + h] + 1e-6f);

  {
    const int dlo = 4 * j, dhi = 64 + 4 * j;
    float4 q0 = *(const float4*)&Q[rowbase + dlo];
    float4 q1 = *(const float4*)&Q[rowbase + dhi];
    q0.x *= iq; q0.y *= iq; q0.z *= iq; q0.w *= iq;
    q1.x *= iq; q1.y *= iq; q1.z *= iq; q1.w *= iq;
    *(float4*)&lq[h][dlo] = q0;
    *(float4*)&lq[h][dhi] = q1;
    float4 k0 = *(const float4*)&K[rowbase + dlo];
    float4 k1 = *(const float4*)&K[rowbase + dhi];
    k0.x *= ik; k0.y *= ik; k0.z *= ik; k0.w *= ik;
    k1.x *= ik; k1.y *= ik; k1.z *= ik; k1.w *= ik;
    *(float4*)&lkk[h][dlo] = k0;
    *(float4*)&lkk[h][dhi] = k1;
    f16x4 v0 = *(const f16x4*)&V[rowbase + dlo];
    f16x4 v1 = *(const f16x4*)&V[rowbase + dhi];
    float4 vf0 = {(float)v0[0], (float)v0[1], (float)v0[2], (float)v0[3]};
    float4 vf1 = {(float)v1[0], (float)v1[1], (float)v1[2], (float)v1[3]};
    *(float4*)&lv[h][dlo] = vf0;
    *(float4*)&lv[h][dhi] = vf1;
  }
  __syncthreads();

  const float4* qr = (const float4*)&lq[h][0];
  const float4* kr = (const float4*)&lkk[j][0];
  float dot = 0.f;
#pragma unroll
  for (int d4 = 0; d4 < 32; d4++) {
    float4 a = qr[d4], b = kr[d4];
    dot = fmaf(a.x, b.x, dot); dot = fmaf(a.y, b.y, dot);
    dot = fmaf(a.z, b.z, dot); dot = fmaf(a.w, b.w, dot);
  }
  float mk = mask[(size_t)pos * 256 + t];
  float x = (dot - 1e9f * mk) * 0.08838834764831845f;  // 1/sqrt(128)
  float mx = x;
#pragma unroll
  for (int m = 1; m < 16; m <<= 1) mx = fmaxf(mx, __shfl_xor(mx, m, 64));
  float e = expf(x - mx);
  float den = e;
#pragma unroll
  for (int m = 1; m < 16; m <<= 1) den += __shfl_xor(den, m, 64);
  float w = e / den;
  wout[(size_t)pos * 256 + t] = w;
  lw[h][j] = w;
  __syncthreads();

  float wreg[16];
#pragma unroll
  for (int k2 = 0; k2 < 16; k2++) wreg[k2] = lw[h][k2];
  float4 a0 = {0.f, 0.f, 0.f, 0.f}, a1 = {0.f, 0.f, 0.f, 0.f};
  const int dlo = 4 * j, dhi = 64 + 4 * j;
#pragma unroll
  for (int k2 = 0; k2 < 16; k2++) {
    float4 v0 = *(const float4*)&lv[k2][dlo];
    float4 v1 = *(const float4*)&lv[k2][dhi];
    float wk = wreg[k2];
    a0.x = fmaf(wk, v0.x, a0.x); a0.y = fmaf(wk, v0.y, a0.y);
    a0.z = fmaf(wk, v0.z, a0.z); a0.w = fmaf(wk, v0.w, a0.w);
    a1.x = fmaf(wk, v1.x, a1.x); a1.y = fmaf(wk, v1.y, a1.y);
    a1.z = fmaf(wk, v1.z, a1.z); a1.w = fmaf(wk, v1.w, a1.w);
  }
  f16x4 o0, o1;
  o0[0] = (_Float16)a0.x; o0[1] = (_Float16)a0.y;
  o0[2] = (_Float16)a0.z; o0[3] = (_Float16)a0.w;
  o1[0] = (_Float16)a1.x; o1[1] = (_Float16)a1.y;
  o1[2] = (_Float16)a1.z; o1[3] = (_Float16)a1.w;
  *(f16x4*)&aout[rowbase + dlo] = o0;
  *(f16x4*)&aout[rowbase + dhi] = o1;
}

// -------------------------------------------------------------------------
extern "C" void kernel_launch(void* const* d_in, const int* in_sizes, int n_in,
                              void* d_out, int out_size, void* d_ws, size_t ws_size,
                              hipStream_t stream) {
  const float* query = (const float*)d_in[0];
  const float* key   = (const float*)d_in[1];
  const float* value = (const float*)d_in[2];
  const float* mask  = (const float*)d_in[3];
  const float* Wq = (const float*)d_in[4];
  const float* Wk = (const float*)d_in[5];
  const float* Wv = (const float*)d_in[6];
  const float* Wo = (const float*)d_in[7];

  float* out  = (float*)d_out;                       // [16384, 2048] fp32
  float* wout = out + (size_t)MROWS * DMODEL;        // [16384, 256] fp32

  const size_t SZ_HALF = (size_t)MROWS * DMODEL * 2; // 67.1 MB
  const size_t SZ_F32  = (size_t)MROWS * DMODEL * 4; // 134.2 MB
  const size_t SZ_W    = (size_t)DMODEL * DMODEL * 2;// 8.4 MB
  const size_t SZ_CS   = (size_t)DMODEL * NHEAD * 4; // 128 KB (fp32)
  const size_t SZ_RS   = (size_t)MROWS * NHEAD * 4;  // 1 MB

  const int n8 = MROWS * DMODEL / 8;
  const int ggrid = (MROWS / 128) * (DMODEL / 128);  // fallback grid
  dim3 wgrid(DMODEL / 32, DMODEL / 32, 5);           // 4 transposes + colsums
  dim3 tgrid(DMODEL / 32, DMODEL / 32);
  dim3 tblk(32, 8);
  dim3 prepgrid(MROWS / 8, 3);
  dim3 rsgrid(MROWS / 8, 2);
  const int dpgrid = (MROWS / 256) * (DMODEL / 256); // 512 blocks
  float* Qbuf = out;   // Q fp32 parked in d_out, overwritten by final GEMM

  const size_t NEED_A = 5 * SZ_HALF + SZ_F32 + 6 * SZ_W + 2 * SZ_CS + 2 * SZ_RS;
  const size_t NEED_B = 3 * SZ_HALF + SZ_F32 + 2 * SZ_W + 2 * SZ_CS + 2 * SZ_RS;
  char* ws = (char*)d_ws;

  if (ws_size >= NEED_A) {
    size_t off = 0;
    _Float16* qh = (_Float16*)(ws + off); off += SZ_HALF;
    _Float16* ql = (_Float16*)(ws + off); off += SZ_HALF;
    _Float16* kh = (_Float16*)(ws + off); off += SZ_HALF;
    _Float16* kl = (_Float16*)(ws + off); off += SZ_HALF;
    _Float16* vh = (_Float16*)(ws + off); off += SZ_HALF;
    float*  Kbuf = (float*)   (ws + off); off += SZ_F32;
    _Float16* wqh = (_Float16*)(ws + off); off += SZ_W;
    _Float16* wql = (_Float16*)(ws + off); off += SZ_W;
    _Float16* wkh = (_Float16*)(ws + off); off += SZ_W;
    _Float16* wkl = (_Float16*)(ws + off); off += SZ_W;
    _Float16* wvh = (_Float16*)(ws + off); off += SZ_W;
    _Float16* woh = (_Float16*)(ws + off); off += SZ_W;
    float* CSq = (float*)(ws + off); off += SZ_CS;
    float* CSk = (float*)(ws + off); off += SZ_CS;
    float* rsQ = (float*)(ws + off); off += SZ_RS;
    float* rsK = (float*)(ws + off); off += SZ_RS;
    _Float16* Vbuf   = qh;   // qh dead after Q-GEMM
    _Float16* attn16 = ql;   // ql dead after Q-GEMM

    weights_prep<<<wgrid, tblk, 0, stream>>>(Wq, Wk, Wv, Wo,
                                             wqh, wql, wkh, wkl, wvh, woh,
                                             CSq, CSk);
    prep_qkv<<<prepgrid, 256, 0, stream>>>(query, key, value, CSq, CSk,
                                           qh, ql, kh, kl, vh, rsQ, rsK);
    gemm_qkv<<<1536, 512, 131072, stream>>>(qh, ql, kh, kl, vh,
                                            wqh, wql, wkh, wkl, wvh,
                                            Qbuf, Kbuf, Vbuf);
    attn_kernel<<<MROWS, 256, 0, stream>>>(Qbuf, Kbuf, Vbuf, mask, rsQ, rsK, wout, attn16);
    gemm_dp<1, 0><<<dpgrid, 512, 65536, stream>>>(attn16, nullptr, woh, nullptr, out, nullptr, MROWS, DMODEL, DMODEL);
    return;
  }

  if (ws_size < NEED_B) return;  // workspace too small — fail visibly

  // Fallback: sequential-reuse layout with proven 2-phase GEMM
  _Float16* a_hi  = (_Float16*)ws;
  _Float16* a_lo  = (_Float16*)(ws + SZ_HALF);
  float*    Kbuf  = (float*)   (ws + 2 * SZ_HALF);
  _Float16* Vbuf  = (_Float16*)(ws + 2 * SZ_HALF + SZ_F32);
  _Float16* wT_hi = (_Float16*)(ws + 3 * SZ_HALF + SZ_F32);
  _Float16* wT_lo = (_Float16*)(ws + 3 * SZ_HALF + SZ_F32 + SZ_W);
  float*    CSq   = (float*)   (ws + 3 * SZ_HALF + SZ_F32 + 2 * SZ_W);
  float*    CSk   = (float*)   (ws + 3 * SZ_HALF + SZ_F32 + 2 * SZ_W + SZ_CS);
  float*    rsQ   = (float*)   (ws + 3 * SZ_HALF + SZ_F32 + 2 * SZ_W + 2 * SZ_CS);
  float*    rsK   = (float*)   (ws + 3 * SZ_HALF + SZ_F32 + 2 * SZ_W + 2 * SZ_CS + SZ_RS);
  _Float16* attn16 = a_hi;

  colsum_f64<<<DMODEL, 256, 0, stream>>>(Wq, CSq);
  colsum_f64<<<DMODEL, 256, 0, stream>>>(Wk, CSk);
  rowsum_v3<<<rsgrid, 256, 0, stream>>>(query, key, CSq, CSk, rsQ, rsK);

  split_f32_f16<<<4096, 256, 0, stream>>>(query, a_hi, a_lo, n8);
  transpose_split<<<tgrid, tblk, 0, stream>>>(Wq, wT_hi, wT_lo);
  gemm_f16<3, 0><<<ggrid, 256, 0, stream>>>(a_hi, a_lo, wT_hi, wT_lo, Qbuf, nullptr, MROWS, DMODEL, DMODEL);
  split_f32_f16<<<4096, 256, 0, stream>>>(key, a_hi, a_lo, n8);
  transpose_split<<<tgrid, tblk, 0, stream>>>(Wk, wT_hi, wT_lo);
  gemm_f16<3, 0><<<ggrid, 256, 0, stream>>>(a_hi, a_lo, wT_hi, wT_lo, Kbuf, nullptr, MROWS, DMODEL, DMODEL);
  split_f32_f16<<<4096, 256, 0, stream>>>(value, a_hi, nullptr, n8);
  transpose_split<<<tgrid, tblk, 0, stream>>>(Wv, wT_hi, nullptr);
  gemm_f16<1, 1><<<ggrid, 256, 0, stream>>>(a_hi, nullptr, wT_hi, nullptr, nullptr, Vbuf, MROWS, DMODEL, DMODEL);
  attn_kernel<<<MROWS, 256, 0, stream>>>(Qbuf, Kbuf, Vbuf, mask, rsQ, rsK, wout, attn16);
  transpose_split<<<tgrid, tblk, 0, stream>>>(Wo, wT_hi, nullptr);
  gemm_f16<1, 0><<<ggrid, 256, 0, stream>>>(attn16, nullptr, wT_hi, nullptr, out, nullptr, MROWS, DMODEL, DMODEL);
}